// Round 3
// baseline (1041.445 us; speedup 1.0000x reference)
//
#include <hip/hip_runtime.h>

#define DEV __device__ __forceinline__

typedef __attribute__((ext_vector_type(4))) float f32x4;
typedef __attribute__((ext_vector_type(8))) short s16x8;
typedef __attribute__((ext_vector_type(8))) unsigned short u16x8;
typedef __attribute__((ext_vector_type(4))) unsigned short u16x4;

// ---- bf16 helpers (RNE) ----
DEV unsigned short f2bf(float f) {
    union { float f; unsigned u; } v; v.f = f;
    unsigned r = v.u + 0x7fffu + ((v.u >> 16) & 1u);
    return (unsigned short)(r >> 16);
}
DEV float bf2f(unsigned short b) {
    union { unsigned u; float f; } v; v.u = ((unsigned)b) << 16;
    return v.f;
}
DEV f32x4 mfma16(s16x8 a, s16x8 b, f32x4 c) {
    return __builtin_amdgcn_mfma_f32_16x16x32_bf16(a, b, c, 0, 0, 0);
}
DEV float sigmoidf_(float x) { return 1.f / (1.f + __expf(-x)); }

// Problem dims
static constexpr int Bc = 2, Lc = 2048, Dc = 2048, Hc = 16, DKc = 128;

// =====================================================================
// GEMM 1: C(bf16) = A(f32, MxK) @ W(f32, KxN).  128x128 tile, BK=32,
// 4 waves each 64x64 (4x4 frags of 16x16x32). blockIdx.z selects weight.
// =====================================================================
struct ProjArgs {
    const float* W[4];
    unsigned short* C[4];
};

__global__ __launch_bounds__(256) void gemm_proj(const float* __restrict__ A,
                                                 ProjArgs pa, int M, int N, int K) {
    __shared__ unsigned short As[128][40];  // [m][k], pad to 40 (80B rows, 16B aligned)
    __shared__ unsigned short Bs[128][40];  // [n][k] (W transposed tile)
    const int tid = threadIdx.x;
    const int lane = tid & 63, wid = tid >> 6;
    const int l15 = lane & 15, lq = lane >> 4;
    const int wr = wid >> 1, wc = wid & 1;
    const int m0 = blockIdx.x * 128, n0 = blockIdx.y * 128;
    const float* __restrict__ W = pa.W[blockIdx.z];
    unsigned short* __restrict__ C = pa.C[blockIdx.z];

    f32x4 acc[4][4] = {};
    for (int kt = 0; kt < K; kt += 32) {
        // stage A tile: 128x32 f32 -> bf16
        for (int it = 0; it < 4; ++it) {
            int idx = it * 256 + tid;            // 1024 float4
            int m = idx >> 3, kk = (idx & 7) * 4;
            f32x4 av = *(const f32x4*)(A + (size_t)(m0 + m) * K + kt + kk);
            u16x4 bv;
            for (int r = 0; r < 4; ++r) bv[r] = f2bf(av[r]);
            *(u16x4*)&As[m][kk] = bv;
        }
        // stage W tile transposed: Bs[n][k]
        for (int it = 0; it < 16; ++it) {
            int idx = it * 256 + tid;
            int n = idx & 127, kk = idx >> 7;
            Bs[n][kk] = f2bf(W[(size_t)(kt + kk) * N + n0 + n]);
        }
        __syncthreads();
        s16x8 af[4];
        for (int m16 = 0; m16 < 4; ++m16)
            af[m16] = *(const s16x8*)&As[wr * 64 + m16 * 16 + l15][8 * lq];
        for (int n16 = 0; n16 < 4; ++n16) {
            s16x8 bf = *(const s16x8*)&Bs[wc * 64 + n16 * 16 + l15][8 * lq];
            for (int m16 = 0; m16 < 4; ++m16)
                acc[m16][n16] = mfma16(af[m16], bf, acc[m16][n16]);
        }
        __syncthreads();
    }
    for (int m16 = 0; m16 < 4; ++m16)
        for (int n16 = 0; n16 < 4; ++n16) {
            int row = m0 + wr * 64 + m16 * 16 + 4 * lq;
            int col = n0 + wc * 64 + n16 * 16 + l15;
            for (int j = 0; j < 4; ++j)
                C[(size_t)(row + j) * N + col] = f2bf(acc[m16][n16][j]);
        }
}

// =====================================================================
// GEMM 2: out(f32) = A(bf16, MxK) @ W(f32, KxN)
// =====================================================================
__global__ __launch_bounds__(256) void gemm_out(const unsigned short* __restrict__ A,
                                                const float* __restrict__ W,
                                                float* __restrict__ C, int M, int N, int K) {
    __shared__ unsigned short As[128][40];
    __shared__ unsigned short Bs[128][40];
    const int tid = threadIdx.x;
    const int lane = tid & 63, wid = tid >> 6;
    const int l15 = lane & 15, lq = lane >> 4;
    const int wr = wid >> 1, wc = wid & 1;
    const int m0 = blockIdx.x * 128, n0 = blockIdx.y * 128;

    f32x4 acc[4][4] = {};
    for (int kt = 0; kt < K; kt += 32) {
        for (int it = 0; it < 2; ++it) {
            int idx = it * 256 + tid;            // 512 u16x8
            int m = idx >> 2, kk = (idx & 3) * 8;
            *(u16x8*)&As[m][kk] = *(const u16x8*)(A + (size_t)(m0 + m) * K + kt + kk);
        }
        for (int it = 0; it < 16; ++it) {
            int idx = it * 256 + tid;
            int n = idx & 127, kk = idx >> 7;
            Bs[n][kk] = f2bf(W[(size_t)(kt + kk) * N + n0 + n]);
        }
        __syncthreads();
        s16x8 af[4];
        for (int m16 = 0; m16 < 4; ++m16)
            af[m16] = *(const s16x8*)&As[wr * 64 + m16 * 16 + l15][8 * lq];
        for (int n16 = 0; n16 < 4; ++n16) {
            s16x8 bf = *(const s16x8*)&Bs[wc * 64 + n16 * 16 + l15][8 * lq];
            for (int m16 = 0; m16 < 4; ++m16)
                acc[m16][n16] = mfma16(af[m16], bf, acc[m16][n16]);
        }
        __syncthreads();
    }
    for (int m16 = 0; m16 < 4; ++m16)
        for (int n16 = 0; n16 < 4; ++n16) {
            int row = m0 + wr * 64 + m16 * 16 + 4 * lq;
            int col = n0 + wc * 64 + n16 * 16 + l15;
            for (int j = 0; j < 4; ++j)
                C[(size_t)(row + j) * N + col] = acc[m16][n16][j];
        }
}

// =====================================================================
// beta: x = hs_row @ Wb + bb; b = sigmoid(x); la = log(1-b) = -softplus(x)
// one block per (b*L + l), 16 threads per head.
// =====================================================================
__global__ __launch_bounds__(256) void beta_kernel(const float* __restrict__ hs,
                                                   const float* __restrict__ Wb,
                                                   const float* __restrict__ bb,
                                                   float* __restrict__ bbuf,
                                                   float* __restrict__ labuf) {
    __shared__ float row[2048];
    const int bl = blockIdx.x, tid = threadIdx.x;
    for (int it = 0; it < 2; ++it) {
        int i4 = it * 256 + tid;
        *(f32x4*)&row[i4 * 4] = *(const f32x4*)(hs + (size_t)bl * 2048 + i4 * 4);
    }
    __syncthreads();
    const int h = tid >> 4, li = tid & 15;
    float p = 0.f;
    for (int j = 0; j < 128; ++j)
        p += row[li + j * 16] * Wb[(size_t)(li + j * 16) * 16 + h];
    for (int o = 8; o; o >>= 1) p += __shfl_down(p, o, 16);
    if (li == 0) {
        float x = p + bb[h];
        bbuf[(size_t)bl * 16 + h] = sigmoidf_(x);
        labuf[(size_t)bl * 16 + h] = -(fmaxf(x, 0.f) + log1pf(__expf(-fabsf(x))));
    }
}

// =====================================================================
// causal depthwise conv (K=4) + SiLU + per-head LayerNorm(DK=128)
// block = 128 threads = one (b,l,h); channel = h*128 + tid
// =====================================================================
__global__ __launch_bounds__(128) void convln_kernel(const unsigned short* __restrict__ src,
                                                     const float* __restrict__ cw,
                                                     const float* __restrict__ cb,
                                                     const float* __restrict__ lw,
                                                     const float* __restrict__ lb,
                                                     unsigned short* __restrict__ dst) {
    const int bl = blockIdx.x;            // b*L + l
    const int h = blockIdx.y;
    const int tid = threadIdx.x;
    const int b = bl >> 11, l = bl & 2047;
    const int c = h * 128 + tid;
    f32x4 w4 = *(const f32x4*)(cw + (size_t)c * 4);
    float y = cb[c];
    for (int j = 0; j < 4; ++j) {
        int lj = l - 3 + j;
        float x = (lj >= 0) ? bf2f(src[((size_t)(b * 2048 + lj)) * 2048 + c]) : 0.f;
        y += w4[j] * x;
    }
    y = y * sigmoidf_(y);   // silu
    // LN across 128 threads (2 waves)
    float s1 = y, s2 = y * y;
    for (int o = 32; o; o >>= 1) { s1 += __shfl_down(s1, o, 64); s2 += __shfl_down(s2, o, 64); }
    __shared__ float red[2][2];
    int w = tid >> 6;
    if ((tid & 63) == 0) { red[w][0] = s1; red[w][1] = s2; }
    __syncthreads();
    float S1 = red[0][0] + red[1][0], S2 = red[0][1] + red[1][1];
    float m = S1 * (1.f / 128.f);
    float var = S2 * (1.f / 128.f) - m * m;
    float r = rsqrtf(var + 1e-5f);
    dst[(size_t)bl * 2048 + c] = f2bf((y - m) * r * lw[tid] + lb[tid]);
}

// =====================================================================
// Chunked gated-delta recurrence (all-MFMA).
// grid = (B*H, 4): block handles one (b,h) and 32 of 128 v-rows.
// chunk C=64; per chunk:
//   P[i][s] = (s<=i) * exp(l_i - l_s) * beta_s * (q_i . k_s)
//   O[i]    = exp(l_i) * S_prev q_i  +  P V
//   S_new   = exp(l_63) S_prev + sum_s exp(l_63-l_s) beta_s v_s k_s^T
// S kept in f32 accumulator registers (each wave owns a (16v x 64k) slab).
// =====================================================================
__global__ __launch_bounds__(256) void recur_kernel(const unsigned short* __restrict__ qln,
                                                    const unsigned short* __restrict__ kln,
                                                    const unsigned short* __restrict__ vp,
                                                    const float* __restrict__ bbuf,
                                                    const float* __restrict__ labuf,
                                                    unsigned short* __restrict__ orec) {
    __shared__ unsigned short Qs[64][136];   // [t][k]
    __shared__ unsigned short Ks[64][136];   // [t][k]
    __shared__ unsigned short Kt[128][72];   // [k][t]   (K transposed)
    __shared__ unsigned short Vt[32][72];    // [v][t]   (V slice transposed)
    __shared__ unsigned short Ps[64][72];    // [i][s]
    __shared__ unsigned short Simg[32][136]; // [v][k]   S_prev bf16 image
    __shared__ float ls[64], es[64], wsc[64], bsc[64];
    __shared__ float gam;

    const int tid = threadIdx.x;
    const int lane = tid & 63, wid = tid >> 6;
    const int l15 = lane & 15, lq = lane >> 4;
    const int bh = blockIdx.x, vs = blockIdx.y;
    const int b = bh >> 4, h = bh & 15;
    const size_t rowBase = (size_t)b * 2048;     // b*L
    const int voff = h * 128 + vs * 32;
    const int vt_own = wid & 1;
    const int ktb = (wid >> 1) * 4;

    f32x4 accS[4] = {};   // S tiles: (vt_own, ktb+q), q=0..3

    for (int ch = 0; ch < 32; ++ch) {
        const int t0 = ch * 64;
        // ---------------- STAGE ----------------
        if (wid == 0) {
            float la = labuf[(rowBase + t0 + lane) * 16 + h];
            float bv = bbuf[(rowBase + t0 + lane) * 16 + h];
            float l = la;
            for (int o = 1; o < 64; o <<= 1) { float n = __shfl_up(l, o, 64); if (lane >= o) l += n; }
            ls[lane] = l;
            es[lane] = __expf(l);
            float l63 = __shfl(l, 63, 64);
            wsc[lane] = __expf(l63 - l) * bv;
            bsc[lane] = bv;
            if (lane == 0) gam = __expf(l63);
            for (int it = 0; it < 16; ++it) {
                int idx = it * 64 + lane;
                int r = idx >> 4, c8 = (idx & 15) * 8;
                *(u16x8*)&Qs[r][c8] = *(const u16x8*)(qln + (rowBase + t0 + r) * 2048 + h * 128 + c8);
            }
        } else if (wid == 1) {
            for (int it = 0; it < 16; ++it) {
                int idx = it * 64 + lane;
                int r = idx >> 4, c8 = (idx & 15) * 8;
                *(u16x8*)&Ks[r][c8] = *(const u16x8*)(kln + (rowBase + t0 + r) * 2048 + h * 128 + c8);
            }
        } else if (wid == 2) {
            // K transpose: lane = t-row -> LDS writes hit 32 distinct banks
            for (int c8 = 0; c8 < 128; c8 += 8) {
                u16x8 kv = *(const u16x8*)(kln + (rowBase + t0 + lane) * 2048 + h * 128 + c8);
                for (int ii = 0; ii < 8; ++ii) Kt[c8 + ii][lane] = kv[ii];
            }
        } else {
            for (int c8 = 0; c8 < 32; c8 += 8) {
                u16x8 vv = *(const u16x8*)(vp + (rowBase + t0 + lane) * 2048 + voff + c8);
                for (int ii = 0; ii < 8; ++ii) Vt[c8 + ii][lane] = vv[ii];
            }
        }
        __syncthreads();

        // ---------------- PHASE 1: P = Q K^T (+decay/mask), Simg <- accS ----
        {
            const int i0 = wid * 16;
            f32x4 accp[4] = {};
            for (int kt = 0; kt < 4; ++kt) {
                s16x8 af = *(const s16x8*)&Qs[i0 + l15][kt * 32 + 8 * lq];
                for (int s16i = 0; s16i < 4; ++s16i) {
                    s16x8 bf = *(const s16x8*)&Ks[s16i * 16 + l15][kt * 32 + 8 * lq];
                    accp[s16i] = mfma16(af, bf, accp[s16i]);
                }
            }
            for (int s16i = 0; s16i < 4; ++s16i)
                for (int j = 0; j < 4; ++j) {
                    int i = i0 + 4 * lq + j;
                    int s = s16i * 16 + l15;
                    float pv = accp[s16i][j];
                    pv = (s <= i) ? pv * __expf(ls[i] - ls[s]) * bsc[s] : 0.f;
                    Ps[i][s] = f2bf(pv);
                }
            for (int q = 0; q < 4; ++q)
                for (int j = 0; j < 4; ++j) {
                    int v = vt_own * 16 + 4 * lq + j;
                    int k = (ktb + q) * 16 + l15;
                    Simg[v][k] = f2bf(accS[q][j]);
                }
        }
        __syncthreads();

        // ---------------- PHASE 3: O = e_i * (Q S^T) + P V ----------------
        {
            const int i0 = wid * 16;
            f32x4 ae[2] = {}, ai[2] = {};
            for (int kt = 0; kt < 4; ++kt) {
                s16x8 af = *(const s16x8*)&Qs[i0 + l15][kt * 32 + 8 * lq];
                for (int vt = 0; vt < 2; ++vt) {
                    s16x8 bf = *(const s16x8*)&Simg[vt * 16 + l15][kt * 32 + 8 * lq];
                    ae[vt] = mfma16(af, bf, ae[vt]);
                }
            }
            for (int st = 0; st < 2; ++st) {
                s16x8 af = *(const s16x8*)&Ps[i0 + l15][st * 32 + 8 * lq];
                for (int vt = 0; vt < 2; ++vt) {
                    s16x8 bf = *(const s16x8*)&Vt[vt * 16 + l15][st * 32 + 8 * lq];
                    ai[vt] = mfma16(af, bf, ai[vt]);
                }
            }
            for (int vt = 0; vt < 2; ++vt)
                for (int j = 0; j < 4; ++j) {
                    int i = i0 + 4 * lq + j;
                    float o = es[i] * ae[vt][j] + ai[vt][j];
                    orec[(rowBase + t0 + i) * 2048 + voff + vt * 16 + l15] = f2bf(o);
                }
        }

        // ---------------- PHASE 4: S = gam*S + (w.V)^T K ----------------
        {
            float g = gam;
            for (int q = 0; q < 4; ++q)
                for (int j = 0; j < 4; ++j) accS[q][j] *= g;
            for (int st = 0; st < 2; ++st) {
                s16x8 vraw = *(const s16x8*)&Vt[vt_own * 16 + l15][st * 32 + 8 * lq];
                s16x8 aw;
                for (int ii = 0; ii < 8; ++ii) {
                    int s = st * 32 + 8 * lq + ii;
                    aw[ii] = (short)f2bf(bf2f((unsigned short)vraw[ii]) * wsc[s]);
                }
                for (int q = 0; q < 4; ++q) {
                    s16x8 bf = *(const s16x8*)&Kt[(ktb + q) * 16 + l15][st * 32 + 8 * lq];
                    accS[q] = mfma16(aw, bf, accS[q]);
                }
            }
        }
        __syncthreads();
    }
}

// =====================================================================
// gate: og = orec * silu(gate_pre)
// =====================================================================
__global__ __launch_bounds__(256) void gate_kernel(const unsigned short* __restrict__ o,
                                                   const unsigned short* __restrict__ g,
                                                   unsigned short* __restrict__ og) {
    size_t i8 = ((size_t)blockIdx.x * 256 + threadIdx.x) * 8;
    u16x8 ov = *(const u16x8*)(o + i8);
    u16x8 gv = *(const u16x8*)(g + i8);
    u16x8 r;
    for (int ii = 0; ii < 8; ++ii) {
        float gf = bf2f(gv[ii]);
        r[ii] = f2bf(bf2f(ov[ii]) * gf * sigmoidf_(gf));
    }
    *(u16x8*)(og + i8) = r;
}

// =====================================================================
extern "C" void kernel_launch(void* const* d_in, const int* in_sizes, int n_in,
                              void* d_out, int out_size, void* d_ws, size_t ws_size,
                              hipStream_t stream) {
    const float* hs  = (const float*)d_in[0];
    const float* Wq  = (const float*)d_in[1];
    const float* Wk  = (const float*)d_in[2];
    const float* Wv  = (const float*)d_in[3];
    const float* Wb  = (const float*)d_in[4];
    const float* bbv = (const float*)d_in[5];
    const float* Wg  = (const float*)d_in[6];
    const float* Wo  = (const float*)d_in[7];
    const float* qcw = (const float*)d_in[8];
    const float* qcb = (const float*)d_in[9];
    const float* kcw = (const float*)d_in[10];
    const float* kcb = (const float*)d_in[11];
    const float* qnw = (const float*)d_in[12];
    const float* qnb = (const float*)d_in[13];
    const float* knw = (const float*)d_in[14];
    const float* knb = (const float*)d_in[15];
    float* out = (float*)d_out;

    char* ws = (char*)d_ws;
    const size_t S2 = (size_t)Bc * Lc * 2048 * 2;   // 16 MiB bf16 plane
    unsigned short* qp   = (unsigned short*)(ws + 0 * S2);
    unsigned short* kp   = (unsigned short*)(ws + 1 * S2);
    unsigned short* vp   = (unsigned short*)(ws + 2 * S2);
    unsigned short* gp   = (unsigned short*)(ws + 3 * S2);
    unsigned short* qln  = (unsigned short*)(ws + 4 * S2);
    unsigned short* kln  = (unsigned short*)(ws + 5 * S2);
    unsigned short* orec = (unsigned short*)(ws + 6 * S2);
    unsigned short* og   = (unsigned short*)(ws + 7 * S2);
    float* bbuf  = (float*)(ws + 8 * S2);
    float* labuf = (float*)(ws + 8 * S2 + (size_t)Bc * Lc * Hc * 4);

    const int M = Bc * Lc;   // 4096

    ProjArgs pa;
    pa.W[0] = Wq; pa.W[1] = Wk; pa.W[2] = Wv; pa.W[3] = Wg;
    pa.C[0] = qp; pa.C[1] = kp; pa.C[2] = vp; pa.C[3] = gp;

    gemm_proj<<<dim3(M / 128, 2048 / 128, 4), dim3(256), 0, stream>>>(hs, pa, M, 2048, 2048);
    beta_kernel<<<dim3(M), dim3(256), 0, stream>>>(hs, Wb, bbv, bbuf, labuf);
    convln_kernel<<<dim3(M, Hc), dim3(128), 0, stream>>>(qp, qcw, qcb, qnw, qnb, qln);
    convln_kernel<<<dim3(M, Hc), dim3(128), 0, stream>>>(kp, kcw, kcb, knw, knb, kln);
    recur_kernel<<<dim3(Bc * Hc, 4), dim3(256), 0, stream>>>(qln, kln, vp, bbuf, labuf, orec);
    gate_kernel<<<dim3(M * 2048 / 8 / 256), dim3(256), 0, stream>>>(orec, gp, og);
    gemm_out<<<dim3(M / 128, 2048 / 128, 1), dim3(256), 0, stream>>>(og, Wo, out, M, 2048, 2048);
}

// Round 6
// 817.783 us; speedup vs baseline: 1.2735x; 1.2735x over previous
//
#include <hip/hip_runtime.h>

#define DEV __device__ __forceinline__

typedef __attribute__((ext_vector_type(4))) float f32x4;
typedef __attribute__((ext_vector_type(8))) short s16x8;
typedef __attribute__((ext_vector_type(8))) unsigned short u16x8;
typedef __attribute__((ext_vector_type(4))) unsigned short u16x4;

// ---- bf16 helpers (RNE) ----
DEV unsigned short f2bf(float f) {
    union { float f; unsigned u; } v; v.f = f;
    unsigned r = v.u + 0x7fffu + ((v.u >> 16) & 1u);
    return (unsigned short)(r >> 16);
}
DEV float bf2f(unsigned short b) {
    union { unsigned u; float f; } v; v.u = ((unsigned)b) << 16;
    return v.f;
}
DEV f32x4 mfma16(s16x8 a, s16x8 b, f32x4 c) {
    return __builtin_amdgcn_mfma_f32_16x16x32_bf16(a, b, c, 0, 0, 0);
}
DEV float sigmoidf_(float x) { return 1.f / (1.f + __expf(-x)); }

// async global->LDS, 16B per lane. lds ptr must be wave-uniform (lane*16 auto).
typedef __attribute__((address_space(3))) unsigned int lds_u32;
typedef const __attribute__((address_space(1))) unsigned int glob_u32;
DEV void gload16(const void* g, void* l) {
    __builtin_amdgcn_global_load_lds((glob_u32*)g, (lds_u32*)l, 16, 0, 0);
}

// Problem dims
static constexpr int Bc = 2, Lc = 2048, Dc = 2048, Hc = 16, DKc = 128;

// =====================================================================
// hs f32 -> bf16 elementwise
// =====================================================================
__global__ __launch_bounds__(256) void hsconv_kernel(const float* __restrict__ src,
                                                     unsigned short* __restrict__ dst) {
    size_t i8 = ((size_t)blockIdx.x * 256 + threadIdx.x) * 8;
    f32x4 a = *(const f32x4*)(src + i8);
    f32x4 b = *(const f32x4*)(src + i8 + 4);
    u16x8 r;
    for (int j = 0; j < 4; ++j) { r[j] = f2bf(a[j]); r[j + 4] = f2bf(b[j]); }
    *(u16x8*)(dst + i8) = r;
}

// =====================================================================
// W f32 [K][N] -> bf16 [N][K] (transpose+convert), 64x64 LDS tiles
// =====================================================================
struct WcArgs { const float* src[5]; unsigned short* dst[5]; };

__global__ __launch_bounds__(256) void wconv_kernel(WcArgs wa) {
    __shared__ unsigned short t[64][66];
    const float* __restrict__ src = wa.src[blockIdx.z];
    unsigned short* __restrict__ dst = wa.dst[blockIdx.z];
    const int k0 = blockIdx.x * 64, n0 = blockIdx.y * 64;
    const int tid = threadIdx.x;
    for (int it = 0; it < 4; ++it) {
        int idx = it * 256 + tid;
        int k = idx >> 4, n = (idx & 15) * 4;
        f32x4 v = *(const f32x4*)(src + (size_t)(k0 + k) * 2048 + n0 + n);
        for (int j = 0; j < 4; ++j) t[k][n + j] = f2bf(v[j]);
    }
    __syncthreads();
    for (int it = 0; it < 4; ++it) {
        int idx = it * 256 + tid;
        int n = idx >> 4, k = (idx & 15) * 4;
        u16x4 o;
        for (int j = 0; j < 4; ++j) o[j] = t[k + j][n];
        *(u16x4*)(dst + (size_t)(n0 + n) * 2048 + k0 + k) = o;
    }
}

// =====================================================================
// m97-structure bf16 GEMM: 128x128 tile, BK=64, global_load_lds staging.
// A [M][K] bf16 row-major; Bt [N][K] bf16 (weight pre-transposed).
// proj variant: 4 weight planes via z, bf16 out. out variant: f32 out.
// =====================================================================
struct GpArgs { const unsigned short* B[4]; unsigned short* C[4]; };

#define GEMM_BODY(A_, Bt_, KDIM)                                                          \
    __shared__ unsigned short As[128 * 64];                                               \
    __shared__ unsigned short Bs[128 * 64];                                               \
    const int tid = threadIdx.x, lane = tid & 63, wid = tid >> 6;                         \
    const int l15 = lane & 15, lq = lane >> 4;                                            \
    const int wr = wid >> 1, wc = wid & 1;                                                \
    const int m0 = blockIdx.x * 128, n0 = blockIdx.y * 128;                               \
    const int rsub = lane >> 3, csub = (lane & 7) * 8;                                    \
    f32x4 acc[4][4] = {};                                                                 \
    for (int kt = 0; kt < KDIM; kt += 64) {                                               \
        for (int j = 0; j < 4; ++j) {                                                     \
            int seg = j * 4 + wid;                                                        \
            gload16(A_ + (size_t)(m0 + seg * 8 + rsub) * KDIM + kt + csub, &As[seg * 512]); \
            gload16(Bt_ + (size_t)(n0 + seg * 8 + rsub) * KDIM + kt + csub, &Bs[seg * 512]); \
        }                                                                                 \
        __syncthreads();                                                                  \
        for (int kh = 0; kh < 2; ++kh) {                                                  \
            s16x8 af[4];                                                                  \
            for (int m16 = 0; m16 < 4; ++m16)                                             \
                af[m16] = *(const s16x8*)&As[(wr * 64 + m16 * 16 + l15) * 64 + kh * 32 + 8 * lq]; \
            for (int n16 = 0; n16 < 4; ++n16) {                                           \
                s16x8 bf = *(const s16x8*)&Bs[(wc * 64 + n16 * 16 + l15) * 64 + kh * 32 + 8 * lq]; \
                for (int m16 = 0; m16 < 4; ++m16)                                         \
                    acc[m16][n16] = mfma16(af[m16], bf, acc[m16][n16]);                   \
            }                                                                             \
        }                                                                                 \
        __syncthreads();                                                                  \
    }

__global__ __launch_bounds__(256) void gemm_proj(const unsigned short* __restrict__ A,
                                                 GpArgs ga, int N, int K) {
    const unsigned short* __restrict__ Bt = ga.B[blockIdx.z];
    GEMM_BODY(A, Bt, K)
    unsigned short* __restrict__ C = ga.C[blockIdx.z];
    for (int m16 = 0; m16 < 4; ++m16)
        for (int n16 = 0; n16 < 4; ++n16) {
            int row = m0 + wr * 64 + m16 * 16 + 4 * lq;
            int col = n0 + wc * 64 + n16 * 16 + l15;
            for (int j = 0; j < 4; ++j)
                C[(size_t)(row + j) * N + col] = f2bf(acc[m16][n16][j]);
        }
}

__global__ __launch_bounds__(256) void gemm_out(const unsigned short* __restrict__ A,
                                                const unsigned short* __restrict__ Bt,
                                                float* __restrict__ C, int N, int K) {
    GEMM_BODY(A, Bt, K)
    for (int m16 = 0; m16 < 4; ++m16)
        for (int n16 = 0; n16 < 4; ++n16) {
            int row = m0 + wr * 64 + m16 * 16 + 4 * lq;
            int col = n0 + wc * 64 + n16 * 16 + l15;
            for (int j = 0; j < 4; ++j)
                C[(size_t)(row + j) * N + col] = acc[m16][n16][j];
        }
}

// =====================================================================
// beta: x = hs_row @ Wb + bb; b = sigmoid(x); la = log(1-b) = -softplus(x)
// =====================================================================
__global__ __launch_bounds__(256) void beta_kernel(const float* __restrict__ hs,
                                                   const float* __restrict__ Wb,
                                                   const float* __restrict__ bb,
                                                   float* __restrict__ bbuf,
                                                   float* __restrict__ labuf) {
    __shared__ float row[2048];
    const int bl = blockIdx.x, tid = threadIdx.x;
    for (int it = 0; it < 2; ++it) {
        int i4 = it * 256 + tid;
        *(f32x4*)&row[i4 * 4] = *(const f32x4*)(hs + (size_t)bl * 2048 + i4 * 4);
    }
    __syncthreads();
    const int h = tid >> 4, li = tid & 15;
    float p = 0.f;
    for (int j = 0; j < 128; ++j)
        p += row[li + j * 16] * Wb[(size_t)(li + j * 16) * 16 + h];
    for (int o = 8; o; o >>= 1) p += __shfl_down(p, o, 16);
    if (li == 0) {
        float x = p + bb[h];
        bbuf[(size_t)bl * 16 + h] = sigmoidf_(x);
        labuf[(size_t)bl * 16 + h] = -(fmaxf(x, 0.f) + log1pf(__expf(-fabsf(x))));
    }
}

// =====================================================================
// causal depthwise conv (K=4) + SiLU + per-head LayerNorm(DK=128)
// =====================================================================
__global__ __launch_bounds__(128) void convln_kernel(const unsigned short* __restrict__ src,
                                                     const float* __restrict__ cw,
                                                     const float* __restrict__ cb,
                                                     const float* __restrict__ lw,
                                                     const float* __restrict__ lb,
                                                     unsigned short* __restrict__ dst) {
    const int bl = blockIdx.x;            // b*L + l
    const int h = blockIdx.y;
    const int tid = threadIdx.x;
    const int b = bl >> 11, l = bl & 2047;
    const int c = h * 128 + tid;
    f32x4 w4 = *(const f32x4*)(cw + (size_t)c * 4);
    float y = cb[c];
    for (int j = 0; j < 4; ++j) {
        int lj = l - 3 + j;
        float x = (lj >= 0) ? bf2f(src[((size_t)(b * 2048 + lj)) * 2048 + c]) : 0.f;
        y += w4[j] * x;
    }
    y = y * sigmoidf_(y);   // silu
    float s1 = y, s2 = y * y;
    for (int o = 32; o; o >>= 1) { s1 += __shfl_down(s1, o, 64); s2 += __shfl_down(s2, o, 64); }
    __shared__ float red[2][2];
    int w = tid >> 6;
    if ((tid & 63) == 0) { red[w][0] = s1; red[w][1] = s2; }
    __syncthreads();
    float S1 = red[0][0] + red[1][0], S2 = red[0][1] + red[1][1];
    float m = S1 * (1.f / 128.f);
    float var = S2 * (1.f / 128.f) - m * m;
    float r = rsqrtf(var + 1e-5f);
    dst[(size_t)bl * 2048 + c] = f2bf((y - m) * r * lw[tid] + lb[tid]);
}

// =====================================================================
// Chunked gated-delta recurrence (all-MFMA). grid=(B*H, 4).
// =====================================================================
__global__ __launch_bounds__(256) void recur_kernel(const unsigned short* __restrict__ qln,
                                                    const unsigned short* __restrict__ kln,
                                                    const unsigned short* __restrict__ vp,
                                                    const float* __restrict__ bbuf,
                                                    const float* __restrict__ labuf,
                                                    unsigned short* __restrict__ orec) {
    __shared__ unsigned short Qs[64][136];   // [t][k]
    __shared__ unsigned short Ks[64][136];   // [t][k]
    __shared__ unsigned short Kt[128][72];   // [k][t]
    __shared__ unsigned short Vt[32][72];    // [v][t]
    __shared__ unsigned short Ps[64][72];    // [i][s]
    __shared__ unsigned short Simg[32][136]; // [v][k]
    __shared__ float ls[64], es[64], wsc[64], bsc[64];
    __shared__ float gam;

    const int tid = threadIdx.x;
    const int lane = tid & 63, wid = tid >> 6;
    const int l15 = lane & 15, lq = lane >> 4;
    const int bh = blockIdx.x, vs = blockIdx.y;
    const int b = bh >> 4, h = bh & 15;
    const size_t rowBase = (size_t)b * 2048;
    const int voff = h * 128 + vs * 32;
    const int vt_own = wid & 1;
    const int ktb = (wid >> 1) * 4;

    f32x4 accS[4] = {};

    for (int ch = 0; ch < 32; ++ch) {
        const int t0 = ch * 64;
        if (wid == 0) {
            float la = labuf[(rowBase + t0 + lane) * 16 + h];
            float bv = bbuf[(rowBase + t0 + lane) * 16 + h];
            float l = la;
            for (int o = 1; o < 64; o <<= 1) { float n = __shfl_up(l, o, 64); if (lane >= o) l += n; }
            ls[lane] = l;
            es[lane] = __expf(l);
            float l63 = __shfl(l, 63, 64);
            wsc[lane] = __expf(l63 - l) * bv;
            bsc[lane] = bv;
            if (lane == 0) gam = __expf(l63);
            for (int it = 0; it < 16; ++it) {
                int idx = it * 64 + lane;
                int r = idx >> 4, c8 = (idx & 15) * 8;
                *(u16x8*)&Qs[r][c8] = *(const u16x8*)(qln + (rowBase + t0 + r) * 2048 + h * 128 + c8);
            }
        } else if (wid == 1) {
            for (int it = 0; it < 16; ++it) {
                int idx = it * 64 + lane;
                int r = idx >> 4, c8 = (idx & 15) * 8;
                *(u16x8*)&Ks[r][c8] = *(const u16x8*)(kln + (rowBase + t0 + r) * 2048 + h * 128 + c8);
            }
        } else if (wid == 2) {
            for (int c8 = 0; c8 < 128; c8 += 8) {
                u16x8 kv = *(const u16x8*)(kln + (rowBase + t0 + lane) * 2048 + h * 128 + c8);
                for (int ii = 0; ii < 8; ++ii) Kt[c8 + ii][lane] = kv[ii];
            }
        } else {
            for (int c8 = 0; c8 < 32; c8 += 8) {
                u16x8 vv = *(const u16x8*)(vp + (rowBase + t0 + lane) * 2048 + voff + c8);
                for (int ii = 0; ii < 8; ++ii) Vt[c8 + ii][lane] = vv[ii];
            }
        }
        __syncthreads();

        {
            const int i0 = wid * 16;
            f32x4 accp[4] = {};
            for (int kt = 0; kt < 4; ++kt) {
                s16x8 af = *(const s16x8*)&Qs[i0 + l15][kt * 32 + 8 * lq];
                for (int s16i = 0; s16i < 4; ++s16i) {
                    s16x8 bf = *(const s16x8*)&Ks[s16i * 16 + l15][kt * 32 + 8 * lq];
                    accp[s16i] = mfma16(af, bf, accp[s16i]);
                }
            }
            for (int s16i = 0; s16i < 4; ++s16i)
                for (int j = 0; j < 4; ++j) {
                    int i = i0 + 4 * lq + j;
                    int s = s16i * 16 + l15;
                    float pv = accp[s16i][j];
                    pv = (s <= i) ? pv * __expf(ls[i] - ls[s]) * bsc[s] : 0.f;
                    Ps[i][s] = f2bf(pv);
                }
            for (int q = 0; q < 4; ++q)
                for (int j = 0; j < 4; ++j) {
                    int v = vt_own * 16 + 4 * lq + j;
                    int k = (ktb + q) * 16 + l15;
                    Simg[v][k] = f2bf(accS[q][j]);
                }
        }
        __syncthreads();

        {
            const int i0 = wid * 16;
            f32x4 ae[2] = {}, ai[2] = {};
            for (int kt = 0; kt < 4; ++kt) {
                s16x8 af = *(const s16x8*)&Qs[i0 + l15][kt * 32 + 8 * lq];
                for (int vt = 0; vt < 2; ++vt) {
                    s16x8 bf = *(const s16x8*)&Simg[vt * 16 + l15][kt * 32 + 8 * lq];
                    ae[vt] = mfma16(af, bf, ae[vt]);
                }
            }
            for (int st = 0; st < 2; ++st) {
                s16x8 af = *(const s16x8*)&Ps[i0 + l15][st * 32 + 8 * lq];
                for (int vt = 0; vt < 2; ++vt) {
                    s16x8 bf = *(const s16x8*)&Vt[vt * 16 + l15][st * 32 + 8 * lq];
                    ai[vt] = mfma16(af, bf, ai[vt]);
                }
            }
            for (int vt = 0; vt < 2; ++vt)
                for (int j = 0; j < 4; ++j) {
                    int i = i0 + 4 * lq + j;
                    float o = es[i] * ae[vt][j] + ai[vt][j];
                    orec[(rowBase + t0 + i) * 2048 + voff + vt * 16 + l15] = f2bf(o);
                }
        }

        {
            float g = gam;
            for (int q = 0; q < 4; ++q)
                for (int j = 0; j < 4; ++j) accS[q][j] *= g;
            for (int st = 0; st < 2; ++st) {
                s16x8 vraw = *(const s16x8*)&Vt[vt_own * 16 + l15][st * 32 + 8 * lq];
                s16x8 aw;
                for (int ii = 0; ii < 8; ++ii) {
                    int s = st * 32 + 8 * lq + ii;
                    aw[ii] = (short)f2bf(bf2f((unsigned short)vraw[ii]) * wsc[s]);
                }
                for (int q = 0; q < 4; ++q) {
                    s16x8 bf = *(const s16x8*)&Kt[(ktb + q) * 16 + l15][st * 32 + 8 * lq];
                    accS[q] = mfma16(aw, bf, accS[q]);
                }
            }
        }
        __syncthreads();
    }
}

// =====================================================================
// gate (in-place on g): g = o * silu(g)
// =====================================================================
__global__ __launch_bounds__(256) void gate_kernel(const unsigned short* __restrict__ o,
                                                   unsigned short* __restrict__ g) {
    size_t i8 = ((size_t)blockIdx.x * 256 + threadIdx.x) * 8;
    u16x8 ov = *(const u16x8*)(o + i8);
    u16x8 gv = *(const u16x8*)(g + i8);
    u16x8 r;
    for (int ii = 0; ii < 8; ++ii) {
        float gf = bf2f(gv[ii]);
        r[ii] = f2bf(bf2f(ov[ii]) * gf * sigmoidf_(gf));
    }
    *(u16x8*)(g + i8) = r;
}

// =====================================================================
extern "C" void kernel_launch(void* const* d_in, const int* in_sizes, int n_in,
                              void* d_out, int out_size, void* d_ws, size_t ws_size,
                              hipStream_t stream) {
    const float* hs  = (const float*)d_in[0];
    const float* Wq  = (const float*)d_in[1];
    const float* Wk  = (const float*)d_in[2];
    const float* Wv  = (const float*)d_in[3];
    const float* Wb  = (const float*)d_in[4];
    const float* bbv = (const float*)d_in[5];
    const float* Wg  = (const float*)d_in[6];
    const float* Wo  = (const float*)d_in[7];
    const float* qcw = (const float*)d_in[8];
    const float* qcb = (const float*)d_in[9];
    const float* kcw = (const float*)d_in[10];
    const float* kcb = (const float*)d_in[11];
    const float* qnw = (const float*)d_in[12];
    const float* qnb = (const float*)d_in[13];
    const float* knw = (const float*)d_in[14];
    const float* knb = (const float*)d_in[15];
    float* out = (float*)d_out;

    char* ws = (char*)d_ws;
    const size_t S2 = (size_t)Bc * Lc * 2048 * 2;        // 16 MiB bf16 activation plane
    const size_t WSb = (size_t)2048 * 2048 * 2;          // 8 MiB bf16 weight plane
    unsigned short* hsb  = (unsigned short*)(ws);                    // 16 MB
    unsigned short* wqt  = (unsigned short*)(ws + S2);               // 8
    unsigned short* wkt  = (unsigned short*)(ws + S2 + 1 * WSb);     // 8
    unsigned short* wvt  = (unsigned short*)(ws + S2 + 2 * WSb);     // 8
    unsigned short* wgt  = (unsigned short*)(ws + S2 + 3 * WSb);     // 8
    unsigned short* wot  = (unsigned short*)(ws + S2 + 4 * WSb);     // 8
    unsigned short* qp   = (unsigned short*)(ws + S2 + 5 * WSb);            // 16
    unsigned short* kp   = (unsigned short*)(ws + S2 + 5 * WSb + 1 * S2);   // 16
    unsigned short* vp   = (unsigned short*)(ws + S2 + 5 * WSb + 2 * S2);   // 16
    unsigned short* gp   = (unsigned short*)(ws + S2 + 5 * WSb + 3 * S2);   // 16
    float* bbuf  = (float*)(ws + S2 + 5 * WSb + 4 * S2);                    // 0.25
    float* labuf = (float*)(ws + S2 + 5 * WSb + 4 * S2 + (size_t)Bc * Lc * Hc * 4);
    // aliases: qln over wqt+wkt (dead after gemm_proj), kln over wvt+wgt,
    // orec over qp (dead after convln_q), gate in-place on gp.
    unsigned short* qln  = wqt;
    unsigned short* kln  = wvt;
    unsigned short* orec = qp;

    const int M = Bc * Lc;   // 4096

    hsconv_kernel<<<dim3(M * 2048 / (256 * 8)), dim3(256), 0, stream>>>(hs, hsb);
    WcArgs wa;
    wa.src[0] = Wq; wa.src[1] = Wk; wa.src[2] = Wv; wa.src[3] = Wg; wa.src[4] = Wo;
    wa.dst[0] = wqt; wa.dst[1] = wkt; wa.dst[2] = wvt; wa.dst[3] = wgt; wa.dst[4] = wot;
    wconv_kernel<<<dim3(32, 32, 5), dim3(256), 0, stream>>>(wa);

    GpArgs ga;
    ga.B[0] = wqt; ga.B[1] = wkt; ga.B[2] = wvt; ga.B[3] = wgt;
    ga.C[0] = qp;  ga.C[1] = kp;  ga.C[2] = vp;  ga.C[3] = gp;
    gemm_proj<<<dim3(M / 128, 2048 / 128, 4), dim3(256), 0, stream>>>(hsb, ga, 2048, 2048);

    beta_kernel<<<dim3(M), dim3(256), 0, stream>>>(hs, Wb, bbv, bbuf, labuf);
    convln_kernel<<<dim3(M, Hc), dim3(128), 0, stream>>>(qp, qcw, qcb, qnw, qnb, qln);
    convln_kernel<<<dim3(M, Hc), dim3(128), 0, stream>>>(kp, kcw, kcb, knw, knb, kln);
    recur_kernel<<<dim3(Bc * Hc, 4), dim3(256), 0, stream>>>(qln, kln, vp, bbuf, labuf, orec);
    gate_kernel<<<dim3(M * 2048 / 8 / 256), dim3(256), 0, stream>>>(orec, gp);
    gemm_out<<<dim3(M / 128, 2048 / 128, 1), dim3(256), 0, stream>>>(gp, wot, out, 2048, 2048);
}

// Round 7
// 599.447 us; speedup vs baseline: 1.7373x; 1.3642x over previous
//
#include <hip/hip_runtime.h>

#define DEV __device__ __forceinline__

typedef __attribute__((ext_vector_type(4))) float f32x4;
typedef __attribute__((ext_vector_type(8))) short s16x8;
typedef __attribute__((ext_vector_type(8))) unsigned short u16x8;
typedef __attribute__((ext_vector_type(4))) unsigned short u16x4;

// ---- bf16 helpers (RNE) ----
DEV unsigned short f2bf(float f) {
    union { float f; unsigned u; } v; v.f = f;
    unsigned r = v.u + 0x7fffu + ((v.u >> 16) & 1u);
    return (unsigned short)(r >> 16);
}
DEV float bf2f(unsigned short b) {
    union { unsigned u; float f; } v; v.u = ((unsigned)b) << 16;
    return v.f;
}
DEV f32x4 mfma16(s16x8 a, s16x8 b, f32x4 c) {
    return __builtin_amdgcn_mfma_f32_16x16x32_bf16(a, b, c, 0, 0, 0);
}
DEV float sigmoidf_(float x) { return 1.f / (1.f + __expf(-x)); }

// async global->LDS, 16B per lane. lds ptr must be wave-uniform (lane*16 auto).
typedef __attribute__((address_space(3))) unsigned int lds_u32;
typedef const __attribute__((address_space(1))) unsigned int glob_u32;
DEV void gload16(const void* g, void* l) {
    __builtin_amdgcn_global_load_lds((glob_u32*)g, (lds_u32*)l, 16, 0, 0);
}

// Problem dims
static constexpr int Bc = 2, Lc = 2048, Dc = 2048, Hc = 16, DKc = 128;

// =====================================================================
// hs f32 -> bf16 elementwise
// =====================================================================
__global__ __launch_bounds__(256) void hsconv_kernel(const float* __restrict__ src,
                                                     unsigned short* __restrict__ dst) {
    size_t i8 = ((size_t)blockIdx.x * 256 + threadIdx.x) * 8;
    f32x4 a = *(const f32x4*)(src + i8);
    f32x4 b = *(const f32x4*)(src + i8 + 4);
    u16x8 r;
    for (int j = 0; j < 4; ++j) { r[j] = f2bf(a[j]); r[j + 4] = f2bf(b[j]); }
    *(u16x8*)(dst + i8) = r;
}

// =====================================================================
// W f32 [K][N] -> bf16 [N][K] (transpose+convert), 64x64 LDS tiles
// =====================================================================
struct WcArgs { const float* src[5]; unsigned short* dst[5]; };

__global__ __launch_bounds__(256) void wconv_kernel(WcArgs wa) {
    __shared__ unsigned short t[64][66];
    const float* __restrict__ src = wa.src[blockIdx.z];
    unsigned short* __restrict__ dst = wa.dst[blockIdx.z];
    const int k0 = blockIdx.x * 64, n0 = blockIdx.y * 64;
    const int tid = threadIdx.x;
    for (int it = 0; it < 4; ++it) {
        int idx = it * 256 + tid;
        int k = idx >> 4, n = (idx & 15) * 4;
        f32x4 v = *(const f32x4*)(src + (size_t)(k0 + k) * 2048 + n0 + n);
        for (int j = 0; j < 4; ++j) t[k][n + j] = f2bf(v[j]);
    }
    __syncthreads();
    for (int it = 0; it < 4; ++it) {
        int idx = it * 256 + tid;
        int n = idx >> 4, k = (idx & 15) * 4;
        u16x4 o;
        for (int j = 0; j < 4; ++j) o[j] = t[k + j][n];
        *(u16x4*)(dst + (size_t)(n0 + n) * 2048 + k0 + k) = o;
    }
}

// =====================================================================
// Wb f32 [2048][16] -> bf16 WbT [16][2048]
// =====================================================================
__global__ __launch_bounds__(256) void wbt_kernel(const float* __restrict__ Wb,
                                                  unsigned short* __restrict__ wbt) {
    int g = blockIdx.x * 256 + threadIdx.x;      // 0..4095
    int n = g >> 8;                               // 0..15
    int k0 = (g & 255) * 8;
    u16x8 r;
    for (int j = 0; j < 8; ++j) r[j] = f2bf(Wb[(size_t)(k0 + j) * 16 + n]);
    *(u16x8*)(wbt + (size_t)n * 2048 + k0) = r;
}

// =====================================================================
// m97-structure bf16 GEMM: 128x128 tile, BK=64, global_load_lds staging.
// =====================================================================
struct GpArgs { const unsigned short* B[4]; unsigned short* C[4]; };

#define GEMM_BODY(A_, Bt_, KDIM)                                                          \
    __shared__ unsigned short As[128 * 64];                                               \
    __shared__ unsigned short Bs[128 * 64];                                               \
    const int tid = threadIdx.x, lane = tid & 63, wid = tid >> 6;                         \
    const int l15 = lane & 15, lq = lane >> 4;                                            \
    const int wr = wid >> 1, wc = wid & 1;                                                \
    const int m0 = blockIdx.x * 128, n0 = blockIdx.y * 128;                               \
    const int rsub = lane >> 3, csub = (lane & 7) * 8;                                    \
    f32x4 acc[4][4] = {};                                                                 \
    for (int kt = 0; kt < KDIM; kt += 64) {                                               \
        for (int j = 0; j < 4; ++j) {                                                     \
            int seg = j * 4 + wid;                                                        \
            gload16(A_ + (size_t)(m0 + seg * 8 + rsub) * KDIM + kt + csub, &As[seg * 512]); \
            gload16(Bt_ + (size_t)(n0 + seg * 8 + rsub) * KDIM + kt + csub, &Bs[seg * 512]); \
        }                                                                                 \
        __syncthreads();                                                                  \
        for (int kh = 0; kh < 2; ++kh) {                                                  \
            s16x8 af[4];                                                                  \
            for (int m16 = 0; m16 < 4; ++m16)                                             \
                af[m16] = *(const s16x8*)&As[(wr * 64 + m16 * 16 + l15) * 64 + kh * 32 + 8 * lq]; \
            for (int n16 = 0; n16 < 4; ++n16) {                                           \
                s16x8 bf = *(const s16x8*)&Bs[(wc * 64 + n16 * 16 + l15) * 64 + kh * 32 + 8 * lq]; \
                for (int m16 = 0; m16 < 4; ++m16)                                         \
                    acc[m16][n16] = mfma16(af[m16], bf, acc[m16][n16]);                   \
            }                                                                             \
        }                                                                                 \
        __syncthreads();                                                                  \
    }

__global__ __launch_bounds__(256) void gemm_proj(const unsigned short* __restrict__ A,
                                                 GpArgs ga, int N, int K) {
    const unsigned short* __restrict__ Bt = ga.B[blockIdx.z];
    GEMM_BODY(A, Bt, K)
    unsigned short* __restrict__ C = ga.C[blockIdx.z];
    for (int m16 = 0; m16 < 4; ++m16)
        for (int n16 = 0; n16 < 4; ++n16) {
            int row = m0 + wr * 64 + m16 * 16 + 4 * lq;
            int col = n0 + wc * 64 + n16 * 16 + l15;
            for (int j = 0; j < 4; ++j)
                C[(size_t)(row + j) * N + col] = f2bf(acc[m16][n16][j]);
        }
}

__global__ __launch_bounds__(256) void gemm_out(const unsigned short* __restrict__ A,
                                                const unsigned short* __restrict__ Bt,
                                                float* __restrict__ C, int N, int K) {
    GEMM_BODY(A, Bt, K)
    for (int m16 = 0; m16 < 4; ++m16)
        for (int n16 = 0; n16 < 4; ++n16) {
            int row = m0 + wr * 64 + m16 * 16 + 4 * lq;
            int col = n0 + wc * 64 + n16 * 16 + l15;
            for (int j = 0; j < 4; ++j)
                C[(size_t)(row + j) * N + col] = acc[m16][n16][j];
        }
}

// =====================================================================
// beta via MFMA skinny GEMM: x = hsb @ WbT^T + bb (M=4096, N=16, K=2048)
// b = sigmoid(x); la = -softplus(x). 64 rows/block, 4 waves x 16 rows.
// =====================================================================
__global__ __launch_bounds__(256) void beta_kernel(const unsigned short* __restrict__ hsb,
                                                   const unsigned short* __restrict__ wbt,
                                                   const float* __restrict__ bb,
                                                   float* __restrict__ bbuf,
                                                   float* __restrict__ labuf) {
    const int tid = threadIdx.x, lane = tid & 63, wid = tid >> 6;
    const int l15 = lane & 15, lq = lane >> 4;
    const int row16 = blockIdx.x * 64 + wid * 16;
    f32x4 acc = {};
    for (int kt = 0; kt < 2048; kt += 32) {
        s16x8 a = *(const s16x8*)(hsb + (size_t)(row16 + l15) * 2048 + kt + 8 * lq);
        s16x8 b = *(const s16x8*)(wbt + (size_t)l15 * 2048 + kt + 8 * lq);
        acc = mfma16(a, b, acc);
    }
    float bias = bb[l15];
    for (int j = 0; j < 4; ++j) {
        int i = row16 + 4 * lq + j;
        float x = acc[j] + bias;
        bbuf[(size_t)i * 16 + l15] = sigmoidf_(x);
        labuf[(size_t)i * 16 + l15] = -(fmaxf(x, 0.f) + log1pf(__expf(-fabsf(x))));
    }
}

// =====================================================================
// causal depthwise conv (K=4) + SiLU + per-head LayerNorm(DK=128)
// =====================================================================
__global__ __launch_bounds__(128) void convln_kernel(const unsigned short* __restrict__ src,
                                                     const float* __restrict__ cw,
                                                     const float* __restrict__ cb,
                                                     const float* __restrict__ lw,
                                                     const float* __restrict__ lb,
                                                     unsigned short* __restrict__ dst) {
    const int bl = blockIdx.x;            // b*L + l
    const int h = blockIdx.y;
    const int tid = threadIdx.x;
    const int b = bl >> 11, l = bl & 2047;
    const int c = h * 128 + tid;
    f32x4 w4 = *(const f32x4*)(cw + (size_t)c * 4);
    float y = cb[c];
    for (int j = 0; j < 4; ++j) {
        int lj = l - 3 + j;
        float x = (lj >= 0) ? bf2f(src[((size_t)(b * 2048 + lj)) * 2048 + c]) : 0.f;
        y += w4[j] * x;
    }
    y = y * sigmoidf_(y);   // silu
    float s1 = y, s2 = y * y;
    for (int o = 32; o; o >>= 1) { s1 += __shfl_down(s1, o, 64); s2 += __shfl_down(s2, o, 64); }
    __shared__ float red[2][2];
    int w = tid >> 6;
    if ((tid & 63) == 0) { red[w][0] = s1; red[w][1] = s2; }
    __syncthreads();
    float S1 = red[0][0] + red[1][0], S2 = red[0][1] + red[1][1];
    float m = S1 * (1.f / 128.f);
    float var = S2 * (1.f / 128.f) - m * m;
    float r = rsqrtf(var + 1e-5f);
    dst[(size_t)bl * 2048 + c] = f2bf((y - m) * r * lw[tid] + lb[tid]);
}

// =====================================================================
// Chunked gated-delta recurrence (all-MFMA). grid=(B*H, 4).
// =====================================================================
__global__ __launch_bounds__(256) void recur_kernel(const unsigned short* __restrict__ qln,
                                                    const unsigned short* __restrict__ kln,
                                                    const unsigned short* __restrict__ vp,
                                                    const float* __restrict__ bbuf,
                                                    const float* __restrict__ labuf,
                                                    unsigned short* __restrict__ orec) {
    __shared__ unsigned short Qs[64][136];   // [t][k]
    __shared__ unsigned short Ks[64][136];   // [t][k]
    __shared__ unsigned short Kt[128][72];   // [k][t]
    __shared__ unsigned short Vt[32][72];    // [v][t]
    __shared__ unsigned short Ps[64][72];    // [i][s]
    __shared__ unsigned short Simg[32][136]; // [v][k]
    __shared__ float ls[64], es[64], wsc[64], bsc[64];
    __shared__ float gam;

    const int tid = threadIdx.x;
    const int lane = tid & 63, wid = tid >> 6;
    const int l15 = lane & 15, lq = lane >> 4;
    const int bh = blockIdx.x, vs = blockIdx.y;
    const int b = bh >> 4, h = bh & 15;
    const size_t rowBase = (size_t)b * 2048;
    const int voff = h * 128 + vs * 32;
    const int vt_own = wid & 1;
    const int ktb = (wid >> 1) * 4;

    f32x4 accS[4] = {};

    for (int ch = 0; ch < 32; ++ch) {
        const int t0 = ch * 64;
        if (wid == 0) {
            float la = labuf[(rowBase + t0 + lane) * 16 + h];
            float bv = bbuf[(rowBase + t0 + lane) * 16 + h];
            float l = la;
            for (int o = 1; o < 64; o <<= 1) { float n = __shfl_up(l, o, 64); if (lane >= o) l += n; }
            ls[lane] = l;
            es[lane] = __expf(l);
            float l63 = __shfl(l, 63, 64);
            wsc[lane] = __expf(l63 - l) * bv;
            bsc[lane] = bv;
            if (lane == 0) gam = __expf(l63);
            for (int it = 0; it < 16; ++it) {
                int idx = it * 64 + lane;
                int r = idx >> 4, c8 = (idx & 15) * 8;
                *(u16x8*)&Qs[r][c8] = *(const u16x8*)(qln + (rowBase + t0 + r) * 2048 + h * 128 + c8);
            }
        } else if (wid == 1) {
            for (int it = 0; it < 16; ++it) {
                int idx = it * 64 + lane;
                int r = idx >> 4, c8 = (idx & 15) * 8;
                *(u16x8*)&Ks[r][c8] = *(const u16x8*)(kln + (rowBase + t0 + r) * 2048 + h * 128 + c8);
            }
        } else if (wid == 2) {
            for (int c8 = 0; c8 < 128; c8 += 8) {
                u16x8 kv = *(const u16x8*)(kln + (rowBase + t0 + lane) * 2048 + h * 128 + c8);
                for (int ii = 0; ii < 8; ++ii) Kt[c8 + ii][lane] = kv[ii];
            }
        } else {
            for (int c8 = 0; c8 < 32; c8 += 8) {
                u16x8 vv = *(const u16x8*)(vp + (rowBase + t0 + lane) * 2048 + voff + c8);
                for (int ii = 0; ii < 8; ++ii) Vt[c8 + ii][lane] = vv[ii];
            }
        }
        __syncthreads();

        {
            const int i0 = wid * 16;
            f32x4 accp[4] = {};
            for (int kt = 0; kt < 4; ++kt) {
                s16x8 af = *(const s16x8*)&Qs[i0 + l15][kt * 32 + 8 * lq];
                for (int s16i = 0; s16i < 4; ++s16i) {
                    s16x8 bf = *(const s16x8*)&Ks[s16i * 16 + l15][kt * 32 + 8 * lq];
                    accp[s16i] = mfma16(af, bf, accp[s16i]);
                }
            }
            for (int s16i = 0; s16i < 4; ++s16i)
                for (int j = 0; j < 4; ++j) {
                    int i = i0 + 4 * lq + j;
                    int s = s16i * 16 + l15;
                    float pv = accp[s16i][j];
                    pv = (s <= i) ? pv * __expf(ls[i] - ls[s]) * bsc[s] : 0.f;
                    Ps[i][s] = f2bf(pv);
                }
            for (int q = 0; q < 4; ++q)
                for (int j = 0; j < 4; ++j) {
                    int v = vt_own * 16 + 4 * lq + j;
                    int k = (ktb + q) * 16 + l15;
                    Simg[v][k] = f2bf(accS[q][j]);
                }
        }
        __syncthreads();

        {
            const int i0 = wid * 16;
            f32x4 ae[2] = {}, ai[2] = {};
            for (int kt = 0; kt < 4; ++kt) {
                s16x8 af = *(const s16x8*)&Qs[i0 + l15][kt * 32 + 8 * lq];
                for (int vt = 0; vt < 2; ++vt) {
                    s16x8 bf = *(const s16x8*)&Simg[vt * 16 + l15][kt * 32 + 8 * lq];
                    ae[vt] = mfma16(af, bf, ae[vt]);
                }
            }
            for (int st = 0; st < 2; ++st) {
                s16x8 af = *(const s16x8*)&Ps[i0 + l15][st * 32 + 8 * lq];
                for (int vt = 0; vt < 2; ++vt) {
                    s16x8 bf = *(const s16x8*)&Vt[vt * 16 + l15][st * 32 + 8 * lq];
                    ai[vt] = mfma16(af, bf, ai[vt]);
                }
            }
            for (int vt = 0; vt < 2; ++vt)
                for (int j = 0; j < 4; ++j) {
                    int i = i0 + 4 * lq + j;
                    float o = es[i] * ae[vt][j] + ai[vt][j];
                    orec[(rowBase + t0 + i) * 2048 + voff + vt * 16 + l15] = f2bf(o);
                }
        }

        {
            float g = gam;
            for (int q = 0; q < 4; ++q)
                for (int j = 0; j < 4; ++j) accS[q][j] *= g;
            for (int st = 0; st < 2; ++st) {
                s16x8 vraw = *(const s16x8*)&Vt[vt_own * 16 + l15][st * 32 + 8 * lq];
                s16x8 aw;
                for (int ii = 0; ii < 8; ++ii) {
                    int s = st * 32 + 8 * lq + ii;
                    aw[ii] = (short)f2bf(bf2f((unsigned short)vraw[ii]) * wsc[s]);
                }
                for (int q = 0; q < 4; ++q) {
                    s16x8 bf = *(const s16x8*)&Kt[(ktb + q) * 16 + l15][st * 32 + 8 * lq];
                    accS[q] = mfma16(aw, bf, accS[q]);
                }
            }
        }
        __syncthreads();
    }
}

// =====================================================================
// gate (in-place on g): g = o * silu(g)
// =====================================================================
__global__ __launch_bounds__(256) void gate_kernel(const unsigned short* __restrict__ o,
                                                   unsigned short* __restrict__ g) {
    size_t i8 = ((size_t)blockIdx.x * 256 + threadIdx.x) * 8;
    u16x8 ov = *(const u16x8*)(o + i8);
    u16x8 gv = *(const u16x8*)(g + i8);
    u16x8 r;
    for (int ii = 0; ii < 8; ++ii) {
        float gf = bf2f(gv[ii]);
        r[ii] = f2bf(bf2f(ov[ii]) * gf * sigmoidf_(gf));
    }
    *(u16x8*)(g + i8) = r;
}

// =====================================================================
extern "C" void kernel_launch(void* const* d_in, const int* in_sizes, int n_in,
                              void* d_out, int out_size, void* d_ws, size_t ws_size,
                              hipStream_t stream) {
    const float* hs  = (const float*)d_in[0];
    const float* Wq  = (const float*)d_in[1];
    const float* Wk  = (const float*)d_in[2];
    const float* Wv  = (const float*)d_in[3];
    const float* Wb  = (const float*)d_in[4];
    const float* bbv = (const float*)d_in[5];
    const float* Wg  = (const float*)d_in[6];
    const float* Wo  = (const float*)d_in[7];
    const float* qcw = (const float*)d_in[8];
    const float* qcb = (const float*)d_in[9];
    const float* kcw = (const float*)d_in[10];
    const float* kcb = (const float*)d_in[11];
    const float* qnw = (const float*)d_in[12];
    const float* qnb = (const float*)d_in[13];
    const float* knw = (const float*)d_in[14];
    const float* knb = (const float*)d_in[15];
    float* out = (float*)d_out;

    char* ws = (char*)d_ws;
    const size_t S2 = (size_t)Bc * Lc * 2048 * 2;        // 16 MiB bf16 activation plane
    const size_t WSb = (size_t)2048 * 2048 * 2;          // 8 MiB bf16 weight plane
    const size_t BB = (size_t)Bc * Lc * Hc * 4;          // 256 KiB
    unsigned short* hsb  = (unsigned short*)(ws);                    // 16 MB
    unsigned short* wqt  = (unsigned short*)(ws + S2);               // 8
    unsigned short* wkt  = (unsigned short*)(ws + S2 + 1 * WSb);     // 8
    unsigned short* wvt  = (unsigned short*)(ws + S2 + 2 * WSb);     // 8
    unsigned short* wgt  = (unsigned short*)(ws + S2 + 3 * WSb);     // 8
    unsigned short* wot  = (unsigned short*)(ws + S2 + 4 * WSb);     // 8
    unsigned short* qp   = (unsigned short*)(ws + S2 + 5 * WSb);            // 16
    unsigned short* kp   = (unsigned short*)(ws + S2 + 5 * WSb + 1 * S2);   // 16
    unsigned short* vp   = (unsigned short*)(ws + S2 + 5 * WSb + 2 * S2);   // 16
    unsigned short* gp   = (unsigned short*)(ws + S2 + 5 * WSb + 3 * S2);   // 16
    float* bbuf  = (float*)(ws + S2 + 5 * WSb + 4 * S2);
    float* labuf = (float*)(ws + S2 + 5 * WSb + 4 * S2 + BB);
    unsigned short* wbt = (unsigned short*)(ws + S2 + 5 * WSb + 4 * S2 + 2 * BB);  // 64 KB
    // aliases: qln over wqt+wkt (dead after gemm_proj), kln over wvt+wgt,
    // orec over qp (dead after convln_q), gate in-place on gp.
    unsigned short* qln  = wqt;
    unsigned short* kln  = wvt;
    unsigned short* orec = qp;

    const int M = Bc * Lc;   // 4096

    hsconv_kernel<<<dim3(M * 2048 / (256 * 8)), dim3(256), 0, stream>>>(hs, hsb);
    WcArgs wa;
    wa.src[0] = Wq; wa.src[1] = Wk; wa.src[2] = Wv; wa.src[3] = Wg; wa.src[4] = Wo;
    wa.dst[0] = wqt; wa.dst[1] = wkt; wa.dst[2] = wvt; wa.dst[3] = wgt; wa.dst[4] = wot;
    wconv_kernel<<<dim3(32, 32, 5), dim3(256), 0, stream>>>(wa);
    wbt_kernel<<<dim3(16), dim3(256), 0, stream>>>(Wb, wbt);

    GpArgs ga;
    ga.B[0] = wqt; ga.B[1] = wkt; ga.B[2] = wvt; ga.B[3] = wgt;
    ga.C[0] = qp;  ga.C[1] = kp;  ga.C[2] = vp;  ga.C[3] = gp;
    gemm_proj<<<dim3(M / 128, 2048 / 128, 4), dim3(256), 0, stream>>>(hsb, ga, 2048, 2048);

    beta_kernel<<<dim3(M / 64), dim3(256), 0, stream>>>(hsb, wbt, bbv, bbuf, labuf);
    convln_kernel<<<dim3(M, Hc), dim3(128), 0, stream>>>(qp, qcw, qcb, qnw, qnb, qln);
    convln_kernel<<<dim3(M, Hc), dim3(128), 0, stream>>>(kp, kcw, kcb, knw, knb, kln);
    recur_kernel<<<dim3(Bc * Hc, 4), dim3(256), 0, stream>>>(qln, kln, vp, bbuf, labuf, orec);
    gate_kernel<<<dim3(M * 2048 / 8 / 256), dim3(256), 0, stream>>>(orec, gp);
    gemm_out<<<dim3(M / 128, 2048 / 128, 1), dim3(256), 0, stream>>>(gp, wot, out, 2048, 2048);
}

// Round 9
// 572.545 us; speedup vs baseline: 1.8190x; 1.0470x over previous
//
#include <hip/hip_runtime.h>

#define DEV __device__ __forceinline__

typedef __attribute__((ext_vector_type(4))) float f32x4;
typedef __attribute__((ext_vector_type(8))) short s16x8;
typedef __attribute__((ext_vector_type(8))) unsigned short u16x8;
typedef __attribute__((ext_vector_type(4))) unsigned short u16x4;

// ---- bf16 helpers (RNE) ----
DEV unsigned short f2bf(float f) {
    union { float f; unsigned u; } v; v.f = f;
    unsigned r = v.u + 0x7fffu + ((v.u >> 16) & 1u);
    return (unsigned short)(r >> 16);
}
DEV float bf2f(unsigned short b) {
    union { unsigned u; float f; } v; v.u = ((unsigned)b) << 16;
    return v.f;
}
DEV f32x4 mfma16(s16x8 a, s16x8 b, f32x4 c) {
    return __builtin_amdgcn_mfma_f32_16x16x32_bf16(a, b, c, 0, 0, 0);
}
DEV float sigmoidf_(float x) { return 1.f / (1.f + __expf(-x)); }

// async global->LDS, 16B per lane. lds ptr must be wave-uniform (lane*16 auto).
typedef __attribute__((address_space(3))) unsigned int lds_u32;
typedef const __attribute__((address_space(1))) unsigned int glob_u32;
DEV void gload16(const void* g, void* l) {
    __builtin_amdgcn_global_load_lds((glob_u32*)g, (lds_u32*)l, 16, 0, 0);
}

// Problem dims
static constexpr int Bc = 2, Lc = 2048, Dc = 2048, Hc = 16, DKc = 128;

// =====================================================================
// hs f32 -> bf16 elementwise
// =====================================================================
__global__ __launch_bounds__(256) void hsconv_kernel(const float* __restrict__ src,
                                                     unsigned short* __restrict__ dst) {
    size_t i8 = ((size_t)blockIdx.x * 256 + threadIdx.x) * 8;
    f32x4 a = *(const f32x4*)(src + i8);
    f32x4 b = *(const f32x4*)(src + i8 + 4);
    u16x8 r;
    for (int j = 0; j < 4; ++j) { r[j] = f2bf(a[j]); r[j + 4] = f2bf(b[j]); }
    *(u16x8*)(dst + i8) = r;
}

// =====================================================================
// W f32 [K][N] -> bf16 [N][K] (transpose+convert), 64x64 LDS tiles
// =====================================================================
struct WcArgs { const float* src[5]; unsigned short* dst[5]; };

__global__ __launch_bounds__(256) void wconv_kernel(WcArgs wa) {
    __shared__ unsigned short t[64][66];
    const float* __restrict__ src = wa.src[blockIdx.z];
    unsigned short* __restrict__ dst = wa.dst[blockIdx.z];
    const int k0 = blockIdx.x * 64, n0 = blockIdx.y * 64;
    const int tid = threadIdx.x;
    for (int it = 0; it < 4; ++it) {
        int idx = it * 256 + tid;
        int k = idx >> 4, n = (idx & 15) * 4;
        f32x4 v = *(const f32x4*)(src + (size_t)(k0 + k) * 2048 + n0 + n);
        for (int j = 0; j < 4; ++j) t[k][n + j] = f2bf(v[j]);
    }
    __syncthreads();
    for (int it = 0; it < 4; ++it) {
        int idx = it * 256 + tid;
        int n = idx >> 4, k = (idx & 15) * 4;
        u16x4 o;
        for (int j = 0; j < 4; ++j) o[j] = t[k + j][n];
        *(u16x4*)(dst + (size_t)(n0 + n) * 2048 + k0 + k) = o;
    }
}

// =====================================================================
// Wb f32 [2048][16] -> bf16 WbT [16][2048]
// =====================================================================
__global__ __launch_bounds__(256) void wbt_kernel(const float* __restrict__ Wb,
                                                  unsigned short* __restrict__ wbt) {
    int g = blockIdx.x * 256 + threadIdx.x;      // 0..4095
    int n = g >> 8;                               // 0..15
    int k0 = (g & 255) * 8;
    u16x8 r;
    for (int j = 0; j < 8; ++j) r[j] = f2bf(Wb[(size_t)(k0 + j) * 16 + n]);
    *(u16x8*)(wbt + (size_t)n * 2048 + k0) = r;
}

// =====================================================================
// m97-structure bf16 GEMM: 128x128 tile, BK=64, global_load_lds staging.
// =====================================================================
struct GpArgs { const unsigned short* B[4]; unsigned short* C[4]; };

#define GEMM_BODY(A_, Bt_, KDIM)                                                          \
    __shared__ unsigned short As[128 * 64];                                               \
    __shared__ unsigned short Bs[128 * 64];                                               \
    const int tid = threadIdx.x, lane = tid & 63, wid = tid >> 6;                         \
    const int l15 = lane & 15, lq = lane >> 4;                                            \
    const int wr = wid >> 1, wc = wid & 1;                                                \
    const int m0 = blockIdx.x * 128, n0 = blockIdx.y * 128;                               \
    const int rsub = lane >> 3, csub = (lane & 7) * 8;                                    \
    f32x4 acc[4][4] = {};                                                                 \
    for (int kt = 0; kt < KDIM; kt += 64) {                                               \
        for (int j = 0; j < 4; ++j) {                                                     \
            int seg = j * 4 + wid;                                                        \
            gload16(A_ + (size_t)(m0 + seg * 8 + rsub) * KDIM + kt + csub, &As[seg * 512]); \
            gload16(Bt_ + (size_t)(n0 + seg * 8 + rsub) * KDIM + kt + csub, &Bs[seg * 512]); \
        }                                                                                 \
        __syncthreads();                                                                  \
        for (int kh = 0; kh < 2; ++kh) {                                                  \
            s16x8 af[4];                                                                  \
            for (int m16 = 0; m16 < 4; ++m16)                                             \
                af[m16] = *(const s16x8*)&As[(wr * 64 + m16 * 16 + l15) * 64 + kh * 32 + 8 * lq]; \
            for (int n16 = 0; n16 < 4; ++n16) {                                           \
                s16x8 bf = *(const s16x8*)&Bs[(wc * 64 + n16 * 16 + l15) * 64 + kh * 32 + 8 * lq]; \
                for (int m16 = 0; m16 < 4; ++m16)                                         \
                    acc[m16][n16] = mfma16(af[m16], bf, acc[m16][n16]);                   \
            }                                                                             \
        }                                                                                 \
        __syncthreads();                                                                  \
    }

__global__ __launch_bounds__(256) void gemm_proj(const unsigned short* __restrict__ A,
                                                 GpArgs ga, int N, int K) {
    const unsigned short* __restrict__ Bt = ga.B[blockIdx.z];
    GEMM_BODY(A, Bt, K)
    unsigned short* __restrict__ C = ga.C[blockIdx.z];
    for (int m16 = 0; m16 < 4; ++m16)
        for (int n16 = 0; n16 < 4; ++n16) {
            int row = m0 + wr * 64 + m16 * 16 + 4 * lq;
            int col = n0 + wc * 64 + n16 * 16 + l15;
            for (int j = 0; j < 4; ++j)
                C[(size_t)(row + j) * N + col] = f2bf(acc[m16][n16][j]);
        }
}

__global__ __launch_bounds__(256) void gemm_out(const unsigned short* __restrict__ A,
                                                const unsigned short* __restrict__ Bt,
                                                float* __restrict__ C, int N, int K) {
    GEMM_BODY(A, Bt, K)
    for (int m16 = 0; m16 < 4; ++m16)
        for (int n16 = 0; n16 < 4; ++n16) {
            int row = m0 + wr * 64 + m16 * 16 + 4 * lq;
            int col = n0 + wc * 64 + n16 * 16 + l15;
            for (int j = 0; j < 4; ++j)
                C[(size_t)(row + j) * N + col] = acc[m16][n16][j];
        }
}

// =====================================================================
// beta via MFMA skinny GEMM: x = hsb @ WbT^T + bb (M=4096, N=16, K=2048)
// =====================================================================
__global__ __launch_bounds__(256) void beta_kernel(const unsigned short* __restrict__ hsb,
                                                   const unsigned short* __restrict__ wbt,
                                                   const float* __restrict__ bb,
                                                   float* __restrict__ bbuf,
                                                   float* __restrict__ labuf) {
    const int tid = threadIdx.x, lane = tid & 63, wid = tid >> 6;
    const int l15 = lane & 15, lq = lane >> 4;
    const int row16 = blockIdx.x * 64 + wid * 16;
    f32x4 acc = {};
    for (int kt = 0; kt < 2048; kt += 32) {
        s16x8 a = *(const s16x8*)(hsb + (size_t)(row16 + l15) * 2048 + kt + 8 * lq);
        s16x8 b = *(const s16x8*)(wbt + (size_t)l15 * 2048 + kt + 8 * lq);
        acc = mfma16(a, b, acc);
    }
    float bias = bb[l15];
    for (int j = 0; j < 4; ++j) {
        int i = row16 + 4 * lq + j;
        float x = acc[j] + bias;
        bbuf[(size_t)i * 16 + l15] = sigmoidf_(x);
        labuf[(size_t)i * 16 + l15] = -(fmaxf(x, 0.f) + log1pf(__expf(-fabsf(x))));
    }
}

// =====================================================================
// causal depthwise conv (K=4) + SiLU + per-head LayerNorm(DK=128)
// one block per (b,l); 256 threads x 8 contiguous channels; head = 16-lane
// group; LN via width-16 shfl_xor tree (no LDS, no syncthreads).
// =====================================================================
__global__ __launch_bounds__(256) void convln_kernel(const unsigned short* __restrict__ src,
                                                     const float* __restrict__ cw,
                                                     const float* __restrict__ cb,
                                                     const float* __restrict__ lw,
                                                     const float* __restrict__ lb,
                                                     unsigned short* __restrict__ dst) {
    const int bl = blockIdx.x;            // b*L + l
    const int tid = threadIdx.x;
    const int b = bl >> 11, l = bl & 2047;
    const int c0 = tid * 8;               // 8 contiguous channels
    const int ch0 = c0 & 127;             // channel-in-head base
    f32x4 wv[8];
    for (int i = 0; i < 8; ++i) wv[i] = *(const f32x4*)(cw + (size_t)(c0 + i) * 4);
    float acc[8];
    {
        f32x4 ca = *(const f32x4*)(cb + c0);
        f32x4 cbv = *(const f32x4*)(cb + c0 + 4);
        for (int i = 0; i < 4; ++i) { acc[i] = ca[i]; acc[4 + i] = cbv[i]; }
    }
    for (int j = 0; j < 4; ++j) {
        int lj = l - 3 + j;
        if (lj < 0) continue;
        u16x8 v = *(const u16x8*)(src + ((size_t)(b * 2048 + lj)) * 2048 + c0);
        for (int i = 0; i < 8; ++i) acc[i] += wv[i][j] * bf2f(v[i]);
    }
    float y[8];
    float s1 = 0.f, s2 = 0.f;
    for (int i = 0; i < 8; ++i) {
        float t = acc[i];
        t = t * sigmoidf_(t);
        y[i] = t; s1 += t; s2 += t * t;
    }
    for (int o = 8; o; o >>= 1) { s1 += __shfl_xor(s1, o, 16); s2 += __shfl_xor(s2, o, 16); }
    float m = s1 * (1.f / 128.f);
    float var = s2 * (1.f / 128.f) - m * m;
    float r = rsqrtf(var + 1e-5f);
    f32x4 lwa = *(const f32x4*)(lw + ch0), lwb = *(const f32x4*)(lw + ch0 + 4);
    f32x4 lba = *(const f32x4*)(lb + ch0), lbb = *(const f32x4*)(lb + ch0 + 4);
    u16x8 outv;
    for (int i = 0; i < 4; ++i) {
        outv[i]     = f2bf((y[i]     - m) * r * lwa[i] + lba[i]);
        outv[4 + i] = f2bf((y[4 + i] - m) * r * lwb[i] + lbb[i]);
    }
    *(u16x8*)(dst + (size_t)bl * 2048 + c0) = outv;
}

// =====================================================================
// Chunked gated-delta recurrence (all-MFMA). grid=(B*H, 4).
// =====================================================================
__global__ __launch_bounds__(256) void recur_kernel(const unsigned short* __restrict__ qln,
                                                    const unsigned short* __restrict__ kln,
                                                    const unsigned short* __restrict__ vp,
                                                    const float* __restrict__ bbuf,
                                                    const float* __restrict__ labuf,
                                                    unsigned short* __restrict__ orec) {
    __shared__ unsigned short Qs[64][136];   // [t][k]
    __shared__ unsigned short Ks[64][136];   // [t][k]
    __shared__ unsigned short Kt[128][72];   // [k][t]
    __shared__ unsigned short Vt[32][72];    // [v][t]
    __shared__ unsigned short Ps[64][72];    // [i][s]
    __shared__ unsigned short Simg[32][136]; // [v][k]
    __shared__ float ls[64], es[64], wsc[64], bsc[64];
    __shared__ float gam;

    const int tid = threadIdx.x;
    const int lane = tid & 63, wid = tid >> 6;
    const int l15 = lane & 15, lq = lane >> 4;
    const int bh = blockIdx.x, vs = blockIdx.y;
    const int b = bh >> 4, h = bh & 15;
    const size_t rowBase = (size_t)b * 2048;
    const int voff = h * 128 + vs * 32;
    const int vt_own = wid & 1;
    const int ktb = (wid >> 1) * 4;

    f32x4 accS[4] = {};

    for (int ch = 0; ch < 32; ++ch) {
        const int t0 = ch * 64;
        if (wid == 0) {
            float la = labuf[(rowBase + t0 + lane) * 16 + h];
            float bv = bbuf[(rowBase + t0 + lane) * 16 + h];
            float l = la;
            for (int o = 1; o < 64; o <<= 1) { float n = __shfl_up(l, o, 64); if (lane >= o) l += n; }
            ls[lane] = l;
            es[lane] = __expf(l);
            float l63 = __shfl(l, 63, 64);
            wsc[lane] = __expf(l63 - l) * bv;
            bsc[lane] = bv;
            if (lane == 0) gam = __expf(l63);
            for (int it = 0; it < 16; ++it) {
                int idx = it * 64 + lane;
                int r = idx >> 4, c8 = (idx & 15) * 8;
                *(u16x8*)&Qs[r][c8] = *(const u16x8*)(qln + (rowBase + t0 + r) * 2048 + h * 128 + c8);
            }
        } else if (wid == 1) {
            for (int it = 0; it < 16; ++it) {
                int idx = it * 64 + lane;
                int r = idx >> 4, c8 = (idx & 15) * 8;
                *(u16x8*)&Ks[r][c8] = *(const u16x8*)(kln + (rowBase + t0 + r) * 2048 + h * 128 + c8);
            }
        } else if (wid == 2) {
            for (int c8 = 0; c8 < 128; c8 += 8) {
                u16x8 kv = *(const u16x8*)(kln + (rowBase + t0 + lane) * 2048 + h * 128 + c8);
                for (int ii = 0; ii < 8; ++ii) Kt[c8 + ii][lane] = kv[ii];
            }
        } else {
            for (int c8 = 0; c8 < 32; c8 += 8) {
                u16x8 vv = *(const u16x8*)(vp + (rowBase + t0 + lane) * 2048 + voff + c8);
                for (int ii = 0; ii < 8; ++ii) Vt[c8 + ii][lane] = vv[ii];
            }
        }
        __syncthreads();

        {
            const int i0 = wid * 16;
            f32x4 accp[4] = {};
            for (int kt = 0; kt < 4; ++kt) {
                s16x8 af = *(const s16x8*)&Qs[i0 + l15][kt * 32 + 8 * lq];
                for (int s16i = 0; s16i < 4; ++s16i) {
                    s16x8 bf = *(const s16x8*)&Ks[s16i * 16 + l15][kt * 32 + 8 * lq];
                    accp[s16i] = mfma16(af, bf, accp[s16i]);
                }
            }
            for (int s16i = 0; s16i < 4; ++s16i)
                for (int j = 0; j < 4; ++j) {
                    int i = i0 + 4 * lq + j;
                    int s = s16i * 16 + l15;
                    float pv = accp[s16i][j];
                    pv = (s <= i) ? pv * __expf(ls[i] - ls[s]) * bsc[s] : 0.f;
                    Ps[i][s] = f2bf(pv);
                }
            for (int q = 0; q < 4; ++q)
                for (int j = 0; j < 4; ++j) {
                    int v = vt_own * 16 + 4 * lq + j;
                    int k = (ktb + q) * 16 + l15;
                    Simg[v][k] = f2bf(accS[q][j]);
                }
        }
        __syncthreads();

        {
            const int i0 = wid * 16;
            f32x4 ae[2] = {}, ai[2] = {};
            for (int kt = 0; kt < 4; ++kt) {
                s16x8 af = *(const s16x8*)&Qs[i0 + l15][kt * 32 + 8 * lq];
                for (int vt = 0; vt < 2; ++vt) {
                    s16x8 bf = *(const s16x8*)&Simg[vt * 16 + l15][kt * 32 + 8 * lq];
                    ae[vt] = mfma16(af, bf, ae[vt]);
                }
            }
            for (int st = 0; st < 2; ++st) {
                s16x8 af = *(const s16x8*)&Ps[i0 + l15][st * 32 + 8 * lq];
                for (int vt = 0; vt < 2; ++vt) {
                    s16x8 bf = *(const s16x8*)&Vt[vt * 16 + l15][st * 32 + 8 * lq];
                    ai[vt] = mfma16(af, bf, ai[vt]);
                }
            }
            for (int vt = 0; vt < 2; ++vt)
                for (int j = 0; j < 4; ++j) {
                    int i = i0 + 4 * lq + j;
                    float o = es[i] * ae[vt][j] + ai[vt][j];
                    orec[(rowBase + t0 + i) * 2048 + voff + vt * 16 + l15] = f2bf(o);
                }
        }

        {
            float g = gam;
            for (int q = 0; q < 4; ++q)
                for (int j = 0; j < 4; ++j) accS[q][j] *= g;
            for (int st = 0; st < 2; ++st) {
                s16x8 vraw = *(const s16x8*)&Vt[vt_own * 16 + l15][st * 32 + 8 * lq];
                s16x8 aw;
                for (int ii = 0; ii < 8; ++ii) {
                    int s = st * 32 + 8 * lq + ii;
                    aw[ii] = (short)f2bf(bf2f((unsigned short)vraw[ii]) * wsc[s]);
                }
                for (int q = 0; q < 4; ++q) {
                    s16x8 bf = *(const s16x8*)&Kt[(ktb + q) * 16 + l15][st * 32 + 8 * lq];
                    accS[q] = mfma16(aw, bf, accS[q]);
                }
            }
        }
        __syncthreads();
    }
}

// =====================================================================
// gate (in-place on g): g = o * silu(g)
// =====================================================================
__global__ __launch_bounds__(256) void gate_kernel(const unsigned short* __restrict__ o,
                                                   unsigned short* __restrict__ g) {
    size_t i8 = ((size_t)blockIdx.x * 256 + threadIdx.x) * 8;
    u16x8 ov = *(const u16x8*)(o + i8);
    u16x8 gv = *(const u16x8*)(g + i8);
    u16x8 r;
    for (int ii = 0; ii < 8; ++ii) {
        float gf = bf2f(gv[ii]);
        r[ii] = f2bf(bf2f(ov[ii]) * gf * sigmoidf_(gf));
    }
    *(u16x8*)(g + i8) = r;
}

// =====================================================================
extern "C" void kernel_launch(void* const* d_in, const int* in_sizes, int n_in,
                              void* d_out, int out_size, void* d_ws, size_t ws_size,
                              hipStream_t stream) {
    const float* hs  = (const float*)d_in[0];
    const float* Wq  = (const float*)d_in[1];
    const float* Wk  = (const float*)d_in[2];
    const float* Wv  = (const float*)d_in[3];
    const float* Wb  = (const float*)d_in[4];
    const float* bbv = (const float*)d_in[5];
    const float* Wg  = (const float*)d_in[6];
    const float* Wo  = (const float*)d_in[7];
    const float* qcw = (const float*)d_in[8];
    const float* qcb = (const float*)d_in[9];
    const float* kcw = (const float*)d_in[10];
    const float* kcb = (const float*)d_in[11];
    const float* qnw = (const float*)d_in[12];
    const float* qnb = (const float*)d_in[13];
    const float* knw = (const float*)d_in[14];
    const float* knb = (const float*)d_in[15];
    float* out = (float*)d_out;

    char* ws = (char*)d_ws;
    const size_t S2 = (size_t)Bc * Lc * 2048 * 2;        // 16 MiB bf16 activation plane
    const size_t WSb = (size_t)2048 * 2048 * 2;          // 8 MiB bf16 weight plane
    const size_t BB = (size_t)Bc * Lc * Hc * 4;          // 256 KiB
    unsigned short* hsb  = (unsigned short*)(ws);                    // 16 MB
    unsigned short* wqt  = (unsigned short*)(ws + S2);               // 8
    unsigned short* wkt  = (unsigned short*)(ws + S2 + 1 * WSb);     // 8
    unsigned short* wvt  = (unsigned short*)(ws + S2 + 2 * WSb);     // 8
    unsigned short* wgt  = (unsigned short*)(ws + S2 + 3 * WSb);     // 8
    unsigned short* wot  = (unsigned short*)(ws + S2 + 4 * WSb);     // 8
    unsigned short* qp   = (unsigned short*)(ws + S2 + 5 * WSb);            // 16
    unsigned short* kp   = (unsigned short*)(ws + S2 + 5 * WSb + 1 * S2);   // 16
    unsigned short* vp   = (unsigned short*)(ws + S2 + 5 * WSb + 2 * S2);   // 16
    unsigned short* gp   = (unsigned short*)(ws + S2 + 5 * WSb + 3 * S2);   // 16
    float* bbuf  = (float*)(ws + S2 + 5 * WSb + 4 * S2);
    float* labuf = (float*)(ws + S2 + 5 * WSb + 4 * S2 + BB);
    unsigned short* wbt = (unsigned short*)(ws + S2 + 5 * WSb + 4 * S2 + 2 * BB);  // 64 KB
    // aliases: qln over wqt+wkt (dead after gemm_proj), kln over wvt+wgt,
    // orec over qp (dead after convln_q), gate in-place on gp.
    unsigned short* qln  = wqt;
    unsigned short* kln  = wvt;
    unsigned short* orec = qp;

    const int M = Bc * Lc;   // 4096

    hsconv_kernel<<<dim3(M * 2048 / (256 * 8)), dim3(256), 0, stream>>>(hs, hsb);
    WcArgs wa;
    wa.src[0] = Wq; wa.src[1] = Wk; wa.src[2] = Wv; wa.src[3] = Wg; wa.src[4] = Wo;
    wa.dst[0] = wqt; wa.dst[1] = wkt; wa.dst[2] = wvt; wa.dst[3] = wgt; wa.dst[4] = wot;
    wconv_kernel<<<dim3(32, 32, 5), dim3(256), 0, stream>>>(wa);
    wbt_kernel<<<dim3(16), dim3(256), 0, stream>>>(Wb, wbt);

    GpArgs ga;
    ga.B[0] = wqt; ga.B[1] = wkt; ga.B[2] = wvt; ga.B[3] = wgt;
    ga.C[0] = qp;  ga.C[1] = kp;  ga.C[2] = vp;  ga.C[3] = gp;
    gemm_proj<<<dim3(M / 128, 2048 / 128, 4), dim3(256), 0, stream>>>(hsb, ga, 2048, 2048);

    beta_kernel<<<dim3(M / 64), dim3(256), 0, stream>>>(hsb, wbt, bbv, bbuf, labuf);
    convln_kernel<<<dim3(M), dim3(256), 0, stream>>>(qp, qcw, qcb, qnw, qnb, qln);
    convln_kernel<<<dim3(M), dim3(256), 0, stream>>>(kp, kcw, kcb, knw, knb, kln);
    recur_kernel<<<dim3(Bc * Hc, 4), dim3(256), 0, stream>>>(qln, kln, vp, bbuf, labuf, orec);
    gate_kernel<<<dim3(M * 2048 / 8 / 256), dim3(256), 0, stream>>>(orec, gp);
    gemm_out<<<dim3(M / 128, 2048 / 128, 1), dim3(256), 0, stream>>>(gp, wot, out, 2048, 2048);
}

// Round 10
// 512.317 us; speedup vs baseline: 2.0328x; 1.1176x over previous
//
#include <hip/hip_runtime.h>

#define DEV __device__ __forceinline__

typedef __attribute__((ext_vector_type(4))) float f32x4;
typedef __attribute__((ext_vector_type(8))) short s16x8;
typedef __attribute__((ext_vector_type(8))) unsigned short u16x8;
typedef __attribute__((ext_vector_type(4))) unsigned short u16x4;

// ---- bf16 helpers (RNE) ----
DEV unsigned short f2bf(float f) {
    union { float f; unsigned u; } v; v.f = f;
    unsigned r = v.u + 0x7fffu + ((v.u >> 16) & 1u);
    return (unsigned short)(r >> 16);
}
DEV float bf2f(unsigned short b) {
    union { unsigned u; float f; } v; v.u = ((unsigned)b) << 16;
    return v.f;
}
DEV f32x4 mfma16(s16x8 a, s16x8 b, f32x4 c) {
    return __builtin_amdgcn_mfma_f32_16x16x32_bf16(a, b, c, 0, 0, 0);
}
DEV float sigmoidf_(float x) { return 1.f / (1.f + __expf(-x)); }

// async global->LDS, 16B per lane. lds ptr must be wave-uniform (lane*16 auto).
typedef __attribute__((address_space(3))) unsigned int lds_u32;
typedef const __attribute__((address_space(1))) unsigned int glob_u32;
DEV void gload16(const void* g, void* l) {
    __builtin_amdgcn_global_load_lds((glob_u32*)g, (lds_u32*)l, 16, 0, 0);
}

// Problem dims
static constexpr int Bc = 2, Lc = 2048, Dc = 2048, Hc = 16, DKc = 128;
static constexpr size_t SLOT = 524288;   // u16 elems per chunk-slot (32 bh x 16384)

// D/S_prev slot: c<16 in plane0 (hsb), c>=16 in plane1 (kp)
DEV unsigned short* dslot(unsigned short* d0, unsigned short* d1, int c, int bh) {
    unsigned short* p = (c < 16) ? d0 + (size_t)c * SLOT : d1 + (size_t)(c - 16) * SLOT;
    return p + (size_t)bh * 16384;
}

// =====================================================================
// hs f32 -> bf16 elementwise
// =====================================================================
__global__ __launch_bounds__(256) void hsconv_kernel(const float* __restrict__ src,
                                                     unsigned short* __restrict__ dst) {
    size_t i8 = ((size_t)blockIdx.x * 256 + threadIdx.x) * 8;
    f32x4 a = *(const f32x4*)(src + i8);
    f32x4 b = *(const f32x4*)(src + i8 + 4);
    u16x8 r;
    for (int j = 0; j < 4; ++j) { r[j] = f2bf(a[j]); r[j + 4] = f2bf(b[j]); }
    *(u16x8*)(dst + i8) = r;
}

// =====================================================================
// W f32 [K][N] -> bf16 [N][K] (transpose+convert), 64x64 LDS tiles
// =====================================================================
struct WcArgs { const float* src[5]; unsigned short* dst[5]; };

__global__ __launch_bounds__(256) void wconv_kernel(WcArgs wa) {
    __shared__ unsigned short t[64][66];
    const float* __restrict__ src = wa.src[blockIdx.z];
    unsigned short* __restrict__ dst = wa.dst[blockIdx.z];
    const int k0 = blockIdx.x * 64, n0 = blockIdx.y * 64;
    const int tid = threadIdx.x;
    for (int it = 0; it < 4; ++it) {
        int idx = it * 256 + tid;
        int k = idx >> 4, n = (idx & 15) * 4;
        f32x4 v = *(const f32x4*)(src + (size_t)(k0 + k) * 2048 + n0 + n);
        for (int j = 0; j < 4; ++j) t[k][n + j] = f2bf(v[j]);
    }
    __syncthreads();
    for (int it = 0; it < 4; ++it) {
        int idx = it * 256 + tid;
        int n = idx >> 4, k = (idx & 15) * 4;
        u16x4 o;
        for (int j = 0; j < 4; ++j) o[j] = t[k + j][n];
        *(u16x4*)(dst + (size_t)(n0 + n) * 2048 + k0 + k) = o;
    }
}

// =====================================================================
// Wb f32 [2048][16] -> bf16 WbT [16][2048]
// =====================================================================
__global__ __launch_bounds__(256) void wbt_kernel(const float* __restrict__ Wb,
                                                  unsigned short* __restrict__ wbt) {
    int g = blockIdx.x * 256 + threadIdx.x;      // 0..4095
    int n = g >> 8;                               // 0..15
    int k0 = (g & 255) * 8;
    u16x8 r;
    for (int j = 0; j < 8; ++j) r[j] = f2bf(Wb[(size_t)(k0 + j) * 16 + n]);
    *(u16x8*)(wbt + (size_t)n * 2048 + k0) = r;
}

// =====================================================================
// m97-structure bf16 GEMM: 128x128 tile, BK=64, global_load_lds staging.
// =====================================================================
struct GpArgs { const unsigned short* B[4]; unsigned short* C[4]; };

#define GEMM_BODY(A_, Bt_, KDIM)                                                          \
    __shared__ unsigned short As[128 * 64];                                               \
    __shared__ unsigned short Bs[128 * 64];                                               \
    const int tid = threadIdx.x, lane = tid & 63, wid = tid >> 6;                         \
    const int l15 = lane & 15, lq = lane >> 4;                                            \
    const int wr = wid >> 1, wc = wid & 1;                                                \
    const int m0 = blockIdx.x * 128, n0 = blockIdx.y * 128;                               \
    const int rsub = lane >> 3, csub = (lane & 7) * 8;                                    \
    f32x4 acc[4][4] = {};                                                                 \
    for (int kt = 0; kt < KDIM; kt += 64) {                                               \
        for (int j = 0; j < 4; ++j) {                                                     \
            int seg = j * 4 + wid;                                                        \
            gload16(A_ + (size_t)(m0 + seg * 8 + rsub) * KDIM + kt + csub, &As[seg * 512]); \
            gload16(Bt_ + (size_t)(n0 + seg * 8 + rsub) * KDIM + kt + csub, &Bs[seg * 512]); \
        }                                                                                 \
        __syncthreads();                                                                  \
        for (int kh = 0; kh < 2; ++kh) {                                                  \
            s16x8 af[4];                                                                  \
            for (int m16 = 0; m16 < 4; ++m16)                                             \
                af[m16] = *(const s16x8*)&As[(wr * 64 + m16 * 16 + l15) * 64 + kh * 32 + 8 * lq]; \
            for (int n16 = 0; n16 < 4; ++n16) {                                           \
                s16x8 bf = *(const s16x8*)&Bs[(wc * 64 + n16 * 16 + l15) * 64 + kh * 32 + 8 * lq]; \
                for (int m16 = 0; m16 < 4; ++m16)                                         \
                    acc[m16][n16] = mfma16(af[m16], bf, acc[m16][n16]);                   \
            }                                                                             \
        }                                                                                 \
        __syncthreads();                                                                  \
    }

__global__ __launch_bounds__(256) void gemm_proj(const unsigned short* __restrict__ A,
                                                 GpArgs ga, int N, int K) {
    const unsigned short* __restrict__ Bt = ga.B[blockIdx.z];
    GEMM_BODY(A, Bt, K)
    unsigned short* __restrict__ C = ga.C[blockIdx.z];
    for (int m16 = 0; m16 < 4; ++m16)
        for (int n16 = 0; n16 < 4; ++n16) {
            int row = m0 + wr * 64 + m16 * 16 + 4 * lq;
            int col = n0 + wc * 64 + n16 * 16 + l15;
            for (int j = 0; j < 4; ++j)
                C[(size_t)(row + j) * N + col] = f2bf(acc[m16][n16][j]);
        }
}

__global__ __launch_bounds__(256) void gemm_out(const unsigned short* __restrict__ A,
                                                const unsigned short* __restrict__ Bt,
                                                float* __restrict__ C, int N, int K) {
    GEMM_BODY(A, Bt, K)
    for (int m16 = 0; m16 < 4; ++m16)
        for (int n16 = 0; n16 < 4; ++n16) {
            int row = m0 + wr * 64 + m16 * 16 + 4 * lq;
            int col = n0 + wc * 64 + n16 * 16 + l15;
            for (int j = 0; j < 4; ++j)
                C[(size_t)(row + j) * N + col] = acc[m16][n16][j];
        }
}

// =====================================================================
// beta via MFMA skinny GEMM
// =====================================================================
__global__ __launch_bounds__(256) void beta_kernel(const unsigned short* __restrict__ hsb,
                                                   const unsigned short* __restrict__ wbt,
                                                   const float* __restrict__ bb,
                                                   float* __restrict__ bbuf,
                                                   float* __restrict__ labuf) {
    const int tid = threadIdx.x, lane = tid & 63, wid = tid >> 6;
    const int l15 = lane & 15, lq = lane >> 4;
    const int row16 = blockIdx.x * 64 + wid * 16;
    f32x4 acc = {};
    for (int kt = 0; kt < 2048; kt += 32) {
        s16x8 a = *(const s16x8*)(hsb + (size_t)(row16 + l15) * 2048 + kt + 8 * lq);
        s16x8 b = *(const s16x8*)(wbt + (size_t)l15 * 2048 + kt + 8 * lq);
        acc = mfma16(a, b, acc);
    }
    float bias = bb[l15];
    for (int j = 0; j < 4; ++j) {
        int i = row16 + 4 * lq + j;
        float x = acc[j] + bias;
        bbuf[(size_t)i * 16 + l15] = sigmoidf_(x);
        labuf[(size_t)i * 16 + l15] = -(fmaxf(x, 0.f) + log1pf(__expf(-fabsf(x))));
    }
}

// =====================================================================
// causal depthwise conv (K=4) + SiLU + per-head LayerNorm(DK=128)
// =====================================================================
__global__ __launch_bounds__(256) void convln_kernel(const unsigned short* __restrict__ src,
                                                     const float* __restrict__ cw,
                                                     const float* __restrict__ cb,
                                                     const float* __restrict__ lw,
                                                     const float* __restrict__ lb,
                                                     unsigned short* __restrict__ dst) {
    const int bl = blockIdx.x;            // b*L + l
    const int tid = threadIdx.x;
    const int b = bl >> 11, l = bl & 2047;
    const int c0 = tid * 8;
    const int ch0 = c0 & 127;
    f32x4 wv[8];
    for (int i = 0; i < 8; ++i) wv[i] = *(const f32x4*)(cw + (size_t)(c0 + i) * 4);
    float acc[8];
    {
        f32x4 ca = *(const f32x4*)(cb + c0);
        f32x4 cbv = *(const f32x4*)(cb + c0 + 4);
        for (int i = 0; i < 4; ++i) { acc[i] = ca[i]; acc[4 + i] = cbv[i]; }
    }
    for (int j = 0; j < 4; ++j) {
        int lj = l - 3 + j;
        if (lj < 0) continue;
        u16x8 v = *(const u16x8*)(src + ((size_t)(b * 2048 + lj)) * 2048 + c0);
        for (int i = 0; i < 8; ++i) acc[i] += wv[i][j] * bf2f(v[i]);
    }
    float y[8];
    float s1 = 0.f, s2 = 0.f;
    for (int i = 0; i < 8; ++i) {
        float t = acc[i];
        t = t * sigmoidf_(t);
        y[i] = t; s1 += t; s2 += t * t;
    }
    for (int o = 8; o; o >>= 1) { s1 += __shfl_xor(s1, o, 16); s2 += __shfl_xor(s2, o, 16); }
    float m = s1 * (1.f / 128.f);
    float var = s2 * (1.f / 128.f) - m * m;
    float r = rsqrtf(var + 1e-5f);
    f32x4 lwa = *(const f32x4*)(lw + ch0), lwb = *(const f32x4*)(lw + ch0 + 4);
    f32x4 lba = *(const f32x4*)(lb + ch0), lbb = *(const f32x4*)(lb + ch0 + 4);
    u16x8 outv;
    for (int i = 0; i < 4; ++i) {
        outv[i]     = f2bf((y[i]     - m) * r * lwa[i] + lba[i]);
        outv[4 + i] = f2bf((y[4 + i] - m) * r * lwb[i] + lbb[i]);
    }
    *(u16x8*)(dst + (size_t)bl * 2048 + c0) = outv;
}

// =====================================================================
// R1: chunk-local recurrence. grid=(B*H, 32 chunks).
//   P[i][s] = (s<=i) e^{l_i-l_s} beta_s (q_i.k_s);  O_local = P V (128 v)
//   D_c[v][k] = sum_s e^{l63-l_s} beta_s V[s][v] K[s][k]  (bf16 -> slot c)
//   gamma_c = e^{l63};  es_buf = e^{l_i}
// =====================================================================
__global__ __launch_bounds__(256) void recur_local(const unsigned short* __restrict__ qln,
                                                   const unsigned short* __restrict__ kln,
                                                   const unsigned short* __restrict__ vp,
                                                   const float* __restrict__ bbuf,
                                                   const float* __restrict__ labuf,
                                                   unsigned short* __restrict__ orec,
                                                   unsigned short* __restrict__ d0,
                                                   unsigned short* __restrict__ d1,
                                                   float* __restrict__ es_buf,
                                                   float* __restrict__ gamma_buf) {
    __shared__ unsigned short Qs[64][136];   // [t][k]
    __shared__ unsigned short Ks[64][136];   // [t][k]
    __shared__ unsigned short Kt[128][72];   // [k][t]
    __shared__ unsigned short Vt[128][72];   // [v][t]
    __shared__ unsigned short Ps[64][72];    // [i][s]
    __shared__ float ls[64], wsc[64], bsc[64];

    const int tid = threadIdx.x;
    const int lane = tid & 63, wid = tid >> 6;
    const int l15 = lane & 15, lq = lane >> 4;
    const int bh = blockIdx.x, c = blockIdx.y;
    const int b = bh >> 4, h = bh & 15;
    const size_t rowBase = (size_t)b * 2048;
    const int t0 = c * 64;

    // ---- stage ----
    if (wid == 0) {
        float la = labuf[(rowBase + t0 + lane) * 16 + h];
        float bv = bbuf[(rowBase + t0 + lane) * 16 + h];
        float l = la;
        for (int o = 1; o < 64; o <<= 1) { float n = __shfl_up(l, o, 64); if (lane >= o) l += n; }
        ls[lane] = l;
        es_buf[(size_t)bh * 2048 + t0 + lane] = __expf(l);
        float l63 = __shfl(l, 63, 64);
        wsc[lane] = __expf(l63 - l) * bv;
        bsc[lane] = bv;
        if (lane == 0) gamma_buf[bh * 32 + c] = __expf(l63);
        for (int it = 0; it < 16; ++it) {
            int idx = it * 64 + lane;
            int r = idx >> 4, c8 = (idx & 15) * 8;
            *(u16x8*)&Qs[r][c8] = *(const u16x8*)(qln + (rowBase + t0 + r) * 2048 + h * 128 + c8);
        }
    } else if (wid == 1) {
        for (int it = 0; it < 16; ++it) {
            int idx = it * 64 + lane;
            int r = idx >> 4, c8 = (idx & 15) * 8;
            *(u16x8*)&Ks[r][c8] = *(const u16x8*)(kln + (rowBase + t0 + r) * 2048 + h * 128 + c8);
        }
    } else if (wid == 2) {
        for (int c8 = 0; c8 < 128; c8 += 8) {
            u16x8 kv = *(const u16x8*)(kln + (rowBase + t0 + lane) * 2048 + h * 128 + c8);
            for (int ii = 0; ii < 8; ++ii) Kt[c8 + ii][lane] = kv[ii];
        }
    } else {
        for (int c8 = 0; c8 < 128; c8 += 8) {
            u16x8 vv = *(const u16x8*)(vp + (rowBase + t0 + lane) * 2048 + h * 128 + c8);
            for (int ii = 0; ii < 8; ++ii) Vt[c8 + ii][lane] = vv[ii];
        }
    }
    __syncthreads();

    // ---- P = QK^T with decay/mask ----
    const int i0 = wid * 16;
    {
        f32x4 accp[4] = {};
        for (int kt = 0; kt < 4; ++kt) {
            s16x8 af = *(const s16x8*)&Qs[i0 + l15][kt * 32 + 8 * lq];
            for (int s16i = 0; s16i < 4; ++s16i) {
                s16x8 bf = *(const s16x8*)&Ks[s16i * 16 + l15][kt * 32 + 8 * lq];
                accp[s16i] = mfma16(af, bf, accp[s16i]);
            }
        }
        for (int s16i = 0; s16i < 4; ++s16i)
            for (int j = 0; j < 4; ++j) {
                int i = i0 + 4 * lq + j;
                int s = s16i * 16 + l15;
                float pv = accp[s16i][j];
                pv = (s <= i) ? pv * __expf(ls[i] - ls[s]) * bsc[s] : 0.f;
                Ps[i][s] = f2bf(pv);
            }
    }
    __syncthreads();

    // ---- O_local = P V (rows i0..i0+15, all 128 v) ----
    {
        f32x4 ai[8] = {};
        for (int st = 0; st < 2; ++st) {
            s16x8 af = *(const s16x8*)&Ps[i0 + l15][st * 32 + 8 * lq];
            for (int vt = 0; vt < 8; ++vt) {
                s16x8 bf = *(const s16x8*)&Vt[vt * 16 + l15][st * 32 + 8 * lq];
                ai[vt] = mfma16(af, bf, ai[vt]);
            }
        }
        for (int vt = 0; vt < 8; ++vt)
            for (int j = 0; j < 4; ++j) {
                int i = i0 + 4 * lq + j;
                orec[(rowBase + t0 + i) * 2048 + h * 128 + vt * 16 + l15] = f2bf(ai[vt][j]);
            }
    }

    // ---- D_c = (wsc.V)^T K  (wave owns 32 v-rows) ----
    if (c < 31) {
        f32x4 accD[2][8] = {};
        for (int st = 0; st < 2; ++st) {
            for (int vtl = 0; vtl < 2; ++vtl) {
                s16x8 vraw = *(const s16x8*)&Vt[(wid * 2 + vtl) * 16 + l15][st * 32 + 8 * lq];
                s16x8 aw;
                for (int ii = 0; ii < 8; ++ii) {
                    int s = st * 32 + 8 * lq + ii;
                    aw[ii] = (short)f2bf(bf2f((unsigned short)vraw[ii]) * wsc[s]);
                }
                for (int q = 0; q < 8; ++q) {
                    s16x8 bfk = *(const s16x8*)&Kt[q * 16 + l15][st * 32 + 8 * lq];
                    accD[vtl][q] = mfma16(aw, bfk, accD[vtl][q]);
                }
            }
        }
        unsigned short* D = dslot(d0, d1, c, bh);
        for (int vtl = 0; vtl < 2; ++vtl)
            for (int q = 0; q < 8; ++q)
                for (int j = 0; j < 4; ++j) {
                    int v = wid * 32 + vtl * 16 + 4 * lq + j;
                    int k = q * 16 + l15;
                    D[v * 128 + k] = f2bf(accD[vtl][q][j]);
                }
    }
}

// =====================================================================
// R2: sequential prefix over chunks (in-place: slot c-1 <- S_prev[c]).
// grid = (B*H * 16 slices); running 8x128 f32 slice in registers.
// =====================================================================
__global__ __launch_bounds__(256) void recur_scan(unsigned short* __restrict__ d0,
                                                  unsigned short* __restrict__ d1,
                                                  const float* __restrict__ gamma_buf) {
    const int bid = blockIdx.x;
    const int bh = bid >> 4, sl = bid & 15;
    const int off = sl * 1024 + threadIdx.x * 4;   // elem offset in 16384-elem plane
    f32x4 running = {};
    for (int c = 0; c < 32; ++c) {
        u16x4 dv;
        if (c < 31) dv = *(const u16x4*)(dslot(d0, d1, c, bh) + off);
        if (c >= 1) {
            u16x4 s;
            for (int j = 0; j < 4; ++j) s[j] = f2bf(running[j]);
            *(u16x4*)(dslot(d0, d1, c - 1, bh) + off) = s;
        }
        if (c < 31) {
            float g = gamma_buf[bh * 32 + c];
            for (int j = 0; j < 4; ++j) running[j] = g * running[j] + bf2f(dv[j]);
        }
    }
}

// =====================================================================
// R3: cross term  orec += e^{l_i} * (S_prev q_i).  grid=(B*H, 31), c=y+1.
// =====================================================================
__global__ __launch_bounds__(256) void recur_cross(const unsigned short* __restrict__ qln,
                                                   unsigned short* __restrict__ orec,
                                                   unsigned short* __restrict__ d0,
                                                   unsigned short* __restrict__ d1,
                                                   const float* __restrict__ es_buf) {
    __shared__ unsigned short Sl[128][136];  // [v][k]
    __shared__ unsigned short Qs[64][136];   // [t][k]
    const int tid = threadIdx.x;
    const int lane = tid & 63, wid = tid >> 6;
    const int l15 = lane & 15, lq = lane >> 4;
    const int bh = blockIdx.x, c = blockIdx.y + 1;
    const int b = bh >> 4, h = bh & 15;
    const size_t rowBase = (size_t)b * 2048;
    const int t0 = c * 64;

    const unsigned short* S = dslot(d0, d1, c - 1, bh);   // S_prev[c] lives at slot c-1
    for (int it = 0; it < 8; ++it) {
        int e = it * 2048 + tid * 8;
        *(u16x8*)&Sl[e >> 7][e & 127] = *(const u16x8*)(S + e);
    }
    for (int it = 0; it < 4; ++it) {
        int e = it * 2048 + tid * 8;
        *(u16x8*)&Qs[e >> 7][e & 127] =
            *(const u16x8*)(qln + (rowBase + t0 + (e >> 7)) * 2048 + h * 128 + (e & 127));
    }
    __syncthreads();

    const int i0 = wid * 16;
    f32x4 ae[8] = {};
    for (int kt = 0; kt < 4; ++kt) {
        s16x8 af = *(const s16x8*)&Qs[i0 + l15][kt * 32 + 8 * lq];
        for (int vt = 0; vt < 8; ++vt) {
            s16x8 bf = *(const s16x8*)&Sl[vt * 16 + l15][kt * 32 + 8 * lq];
            ae[vt] = mfma16(af, bf, ae[vt]);
        }
    }
    for (int j = 0; j < 4; ++j) {
        int i = i0 + 4 * lq + j;
        float e = es_buf[(size_t)bh * 2048 + t0 + i];
        size_t base = (rowBase + t0 + i) * 2048 + h * 128;
        for (int vt = 0; vt < 8; ++vt) {
            size_t a = base + vt * 16 + l15;
            orec[a] = f2bf(bf2f(orec[a]) + e * ae[vt][j]);
        }
    }
}

// =====================================================================
// gate (in-place on g): g = o * silu(g)
// =====================================================================
__global__ __launch_bounds__(256) void gate_kernel(const unsigned short* __restrict__ o,
                                                   unsigned short* __restrict__ g) {
    size_t i8 = ((size_t)blockIdx.x * 256 + threadIdx.x) * 8;
    u16x8 ov = *(const u16x8*)(o + i8);
    u16x8 gv = *(const u16x8*)(g + i8);
    u16x8 r;
    for (int ii = 0; ii < 8; ++ii) {
        float gf = bf2f(gv[ii]);
        r[ii] = f2bf(bf2f(ov[ii]) * gf * sigmoidf_(gf));
    }
    *(u16x8*)(g + i8) = r;
}

// =====================================================================
extern "C" void kernel_launch(void* const* d_in, const int* in_sizes, int n_in,
                              void* d_out, int out_size, void* d_ws, size_t ws_size,
                              hipStream_t stream) {
    const float* hs  = (const float*)d_in[0];
    const float* Wq  = (const float*)d_in[1];
    const float* Wk  = (const float*)d_in[2];
    const float* Wv  = (const float*)d_in[3];
    const float* Wb  = (const float*)d_in[4];
    const float* bbv = (const float*)d_in[5];
    const float* Wg  = (const float*)d_in[6];
    const float* Wo  = (const float*)d_in[7];
    const float* qcw = (const float*)d_in[8];
    const float* qcb = (const float*)d_in[9];
    const float* kcw = (const float*)d_in[10];
    const float* kcb = (const float*)d_in[11];
    const float* qnw = (const float*)d_in[12];
    const float* qnb = (const float*)d_in[13];
    const float* knw = (const float*)d_in[14];
    const float* knb = (const float*)d_in[15];
    float* out = (float*)d_out;

    char* ws = (char*)d_ws;
    const size_t S2 = (size_t)Bc * Lc * 2048 * 2;        // 16 MiB bf16 activation plane
    const size_t WSb = (size_t)2048 * 2048 * 2;          // 8 MiB bf16 weight plane
    const size_t BB = (size_t)Bc * Lc * Hc * 4;          // 256 KiB
    unsigned short* hsb  = (unsigned short*)(ws);                    // 16 MB (-> D slots 0..15)
    unsigned short* wqt  = (unsigned short*)(ws + S2);               // 8
    unsigned short* wkt  = (unsigned short*)(ws + S2 + 1 * WSb);     // 8
    unsigned short* wvt  = (unsigned short*)(ws + S2 + 2 * WSb);     // 8
    unsigned short* wgt  = (unsigned short*)(ws + S2 + 3 * WSb);     // 8
    unsigned short* wot  = (unsigned short*)(ws + S2 + 4 * WSb);     // 8
    unsigned short* qp   = (unsigned short*)(ws + S2 + 5 * WSb);            // 16
    unsigned short* kp   = (unsigned short*)(ws + S2 + 5 * WSb + 1 * S2);   // 16 (-> D slots 16..30)
    unsigned short* vp   = (unsigned short*)(ws + S2 + 5 * WSb + 2 * S2);   // 16
    unsigned short* gp   = (unsigned short*)(ws + S2 + 5 * WSb + 3 * S2);   // 16
    char* tail = ws + S2 + 5 * WSb + 4 * S2;
    float* bbuf  = (float*)(tail);
    float* labuf = (float*)(tail + BB);
    unsigned short* wbt = (unsigned short*)(tail + 2 * BB);          // 64 KB
    float* es_buf = (float*)(tail + 2 * BB + 65536);                 // 256 KB
    float* gamma_buf = (float*)(tail + 2 * BB + 65536 + 262144);     // 4 KB
    // aliases: qln over wqt+wkt (dead after gemm_proj), kln over wvt+wgt,
    // orec over qp (dead after convln_q). D/S_prev slots over hsb (dead after
    // beta) + kp (dead after convln_k). gate in-place on gp.
    unsigned short* qln  = wqt;
    unsigned short* kln  = wvt;
    unsigned short* orec = qp;

    const int M = Bc * Lc;   // 4096

    hsconv_kernel<<<dim3(M * 2048 / (256 * 8)), dim3(256), 0, stream>>>(hs, hsb);
    WcArgs wa;
    wa.src[0] = Wq; wa.src[1] = Wk; wa.src[2] = Wv; wa.src[3] = Wg; wa.src[4] = Wo;
    wa.dst[0] = wqt; wa.dst[1] = wkt; wa.dst[2] = wvt; wa.dst[3] = wgt; wa.dst[4] = wot;
    wconv_kernel<<<dim3(32, 32, 5), dim3(256), 0, stream>>>(wa);
    wbt_kernel<<<dim3(16), dim3(256), 0, stream>>>(Wb, wbt);

    GpArgs ga;
    ga.B[0] = wqt; ga.B[1] = wkt; ga.B[2] = wvt; ga.B[3] = wgt;
    ga.C[0] = qp;  ga.C[1] = kp;  ga.C[2] = vp;  ga.C[3] = gp;
    gemm_proj<<<dim3(M / 128, 2048 / 128, 4), dim3(256), 0, stream>>>(hsb, ga, 2048, 2048);

    beta_kernel<<<dim3(M / 64), dim3(256), 0, stream>>>(hsb, wbt, bbv, bbuf, labuf);
    convln_kernel<<<dim3(M), dim3(256), 0, stream>>>(qp, qcw, qcb, qnw, qnb, qln);
    convln_kernel<<<dim3(M), dim3(256), 0, stream>>>(kp, kcw, kcb, knw, knb, kln);

    recur_local<<<dim3(Bc * Hc, 32), dim3(256), 0, stream>>>(qln, kln, vp, bbuf, labuf,
                                                             orec, hsb, kp, es_buf, gamma_buf);
    recur_scan<<<dim3(Bc * Hc * 16), dim3(256), 0, stream>>>(hsb, kp, gamma_buf);
    recur_cross<<<dim3(Bc * Hc, 31), dim3(256), 0, stream>>>(qln, orec, hsb, kp, es_buf);

    gate_kernel<<<dim3(M * 2048 / 8 / 256), dim3(256), 0, stream>>>(orec, gp);
    gemm_out<<<dim3(M / 128, 2048 / 128, 1), dim3(256), 0, stream>>>(gp, wot, out, 2048, 2048);
}